// Round 2
// baseline (2074.996 us; speedup 1.0000x reference)
//
#include <hip/hip_runtime.h>

// Problem constants (from reference)
#define NN 50000
#define NE 800000
#define HH 64
#define LL 4
#define GG 500
#define CC 10
#define BN_EPS 1e-5f

// ---------------------------------------------------------------------------
// CSR build: histogram of dst, exclusive scan, scatter src ids.
// ---------------------------------------------------------------------------
__global__ __launch_bounds__(256) void k_hist(const int* __restrict__ dst, int* __restrict__ deg) {
    int e = blockIdx.x * 256 + threadIdx.x;
    if (e < NE) atomicAdd(&deg[dst[e]], 1);
}

__global__ __launch_bounds__(1024) void k_scan(const int* __restrict__ deg, int* __restrict__ row_ptr) {
    __shared__ int sums[1024];
    int tid = threadIdx.x;
    const int chunk = (NN + 1023) / 1024;   // 49
    int start = tid * chunk;
    int end = start + chunk;
    if (start > NN) start = NN;
    if (end > NN) end = NN;
    int s = 0;
    for (int i = start; i < end; ++i) s += deg[i];
    sums[tid] = s;
    __syncthreads();
    for (int off = 1; off < 1024; off <<= 1) {
        int v = 0;
        if (tid >= off) v = sums[tid - off];
        __syncthreads();
        if (tid >= off) sums[tid] += v;
        __syncthreads();
    }
    int run = (tid == 0) ? 0 : sums[tid - 1];
    for (int i = start; i < end; ++i) { row_ptr[i] = run; run += deg[i]; }
    if (tid == 1023) row_ptr[NN] = sums[1023];
}

__global__ __launch_bounds__(256) void k_scatter(const int* __restrict__ src, const int* __restrict__ dst,
                                                 const int* __restrict__ row_ptr, int* __restrict__ cursor,
                                                 int* __restrict__ col) {
    int e = blockIdx.x * 256 + threadIdx.x;
    if (e < NE) {
        int d = dst[e];
        int pos = atomicAdd(&cursor[d], 1);
        col[row_ptr[d] + pos] = src[e];
    }
}

// ---------------------------------------------------------------------------
// Fused GIN layer, 4 nodes per wave.
//   16-lane group per node; lane holds float4 (4 features). Gather with x4
//   unroll (up to 16 row-loads in flight per wave), GEMMs via width-16 shfl
//   broadcast + float4 LDS weight reads, BN+ReLU folded, fused JK-pool atomic.
// ---------------------------------------------------------------------------
__global__ __launch_bounds__(256, 4) void k_layer(
    const float* __restrict__ h_in, float* __restrict__ h_out,
    const int* __restrict__ row_ptr, const int* __restrict__ col,
    const int* __restrict__ batch,
    const float* __restrict__ W1, const float* __restrict__ lb1,
    const float* __restrict__ g1, const float* __restrict__ bb1,
    const float* __restrict__ m1, const float* __restrict__ v1,
    const float* __restrict__ W2, const float* __restrict__ lb2,
    const float* __restrict__ g2, const float* __restrict__ bb2,
    const float* __restrict__ m2, const float* __restrict__ v2,
    float* __restrict__ pooled, int layer)
{
    __shared__ float W1s[64 * 64];
    __shared__ float W2s[64 * 64];
    __shared__ float sc1[64], sh1[64], sc2[64], sh2[64];
    int tid = threadIdx.x;
    {
        const float4* a = (const float4*)W1;
        const float4* b = (const float4*)W2;
        float4* A = (float4*)W1s;
        float4* B = (float4*)W2s;
        for (int i = tid; i < 1024; i += 256) { A[i] = a[i]; B[i] = b[i]; }
    }
    if (tid < 64) {
        float s1 = g1[tid] * rsqrtf(v1[tid] + BN_EPS);
        sc1[tid] = s1;
        sh1[tid] = (lb1[tid] - m1[tid]) * s1 + bb1[tid];
        float s2 = g2[tid] * rsqrtf(v2[tid] + BN_EPS);
        sc2[tid] = s2;
        sh2[tid] = (lb2[tid] - m2[tid]) * s2 + bb2[tid];
    }
    __syncthreads();

    int lane  = tid & 63;
    int wave  = tid >> 6;
    int glane = lane & 15;   // lane within 16-group
    int grp   = lane >> 4;   // group (node slot) within wave

    for (int nb = blockIdx.x * 16 + wave * 4; nb < NN; nb += gridDim.x * 16) {
        int n = nb + grp;
        bool valid = (n < NN);
        float4 acc = make_float4(0.f, 0.f, 0.f, 0.f);
        int j = 0, fin = 0;
        if (valid) {
            acc = ((const float4*)(h_in + (size_t)n * HH))[glane];
            j = row_ptr[n];
            fin = row_ptr[n + 1];
        }
        float4 acc2 = make_float4(0.f, 0.f, 0.f, 0.f);
        for (; j + 4 <= fin; j += 4) {
            int s0 = col[j], s1i = col[j + 1], s2i = col[j + 2], s3i = col[j + 3];
            float4 v0 = ((const float4*)(h_in + (size_t)s0  * HH))[glane];
            float4 va = ((const float4*)(h_in + (size_t)s1i * HH))[glane];
            float4 vb = ((const float4*)(h_in + (size_t)s2i * HH))[glane];
            float4 vc = ((const float4*)(h_in + (size_t)s3i * HH))[glane];
            acc.x  += v0.x + vb.x;  acc.y  += v0.y + vb.y;
            acc.z  += v0.z + vb.z;  acc.w  += v0.w + vb.w;
            acc2.x += va.x + vc.x;  acc2.y += va.y + vc.y;
            acc2.z += va.z + vc.z;  acc2.w += va.w + vc.w;
        }
        for (; j < fin; ++j) {
            int s0 = col[j];
            float4 v0 = ((const float4*)(h_in + (size_t)s0 * HH))[glane];
            acc.x += v0.x; acc.y += v0.y; acc.z += v0.z; acc.w += v0.w;
        }
        acc.x += acc2.x; acc.y += acc2.y; acc.z += acc2.z; acc.w += acc2.w;

        // ---- GEMM1 (+BN1+ReLU): lane computes c = glane*4 .. glane*4+3
        float4 d = make_float4(0.f, 0.f, 0.f, 0.f);
        #pragma unroll
        for (int kl = 0; kl < 16; ++kl) {
            float ax = __shfl(acc.x, kl, 16);
            float ay = __shfl(acc.y, kl, 16);
            float az = __shfl(acc.z, kl, 16);
            float aw = __shfl(acc.w, kl, 16);
            float4 w0 = *(const float4*)&W1s[(kl * 4 + 0) * HH + glane * 4];
            float4 w1 = *(const float4*)&W1s[(kl * 4 + 1) * HH + glane * 4];
            float4 w2 = *(const float4*)&W1s[(kl * 4 + 2) * HH + glane * 4];
            float4 w3 = *(const float4*)&W1s[(kl * 4 + 3) * HH + glane * 4];
            d.x = fmaf(ax, w0.x, d.x); d.y = fmaf(ax, w0.y, d.y); d.z = fmaf(ax, w0.z, d.z); d.w = fmaf(ax, w0.w, d.w);
            d.x = fmaf(ay, w1.x, d.x); d.y = fmaf(ay, w1.y, d.y); d.z = fmaf(ay, w1.z, d.z); d.w = fmaf(ay, w1.w, d.w);
            d.x = fmaf(az, w2.x, d.x); d.y = fmaf(az, w2.y, d.y); d.z = fmaf(az, w2.z, d.z); d.w = fmaf(az, w2.w, d.w);
            d.x = fmaf(aw, w3.x, d.x); d.y = fmaf(aw, w3.y, d.y); d.z = fmaf(aw, w3.z, d.z); d.w = fmaf(aw, w3.w, d.w);
        }
        float4 s1v = *(const float4*)&sc1[glane * 4];
        float4 h1v = *(const float4*)&sh1[glane * 4];
        float4 z;
        z.x = fmaxf(fmaf(d.x, s1v.x, h1v.x), 0.f);
        z.y = fmaxf(fmaf(d.y, s1v.y, h1v.y), 0.f);
        z.z = fmaxf(fmaf(d.z, s1v.z, h1v.z), 0.f);
        z.w = fmaxf(fmaf(d.w, s1v.w, h1v.w), 0.f);

        // ---- GEMM2 (+BN2+ReLU)
        float4 d2 = make_float4(0.f, 0.f, 0.f, 0.f);
        #pragma unroll
        for (int kl = 0; kl < 16; ++kl) {
            float ax = __shfl(z.x, kl, 16);
            float ay = __shfl(z.y, kl, 16);
            float az = __shfl(z.z, kl, 16);
            float aw = __shfl(z.w, kl, 16);
            float4 w0 = *(const float4*)&W2s[(kl * 4 + 0) * HH + glane * 4];
            float4 w1 = *(const float4*)&W2s[(kl * 4 + 1) * HH + glane * 4];
            float4 w2 = *(const float4*)&W2s[(kl * 4 + 2) * HH + glane * 4];
            float4 w3 = *(const float4*)&W2s[(kl * 4 + 3) * HH + glane * 4];
            d2.x = fmaf(ax, w0.x, d2.x); d2.y = fmaf(ax, w0.y, d2.y); d2.z = fmaf(ax, w0.z, d2.z); d2.w = fmaf(ax, w0.w, d2.w);
            d2.x = fmaf(ay, w1.x, d2.x); d2.y = fmaf(ay, w1.y, d2.y); d2.z = fmaf(ay, w1.z, d2.z); d2.w = fmaf(ay, w1.w, d2.w);
            d2.x = fmaf(az, w2.x, d2.x); d2.y = fmaf(az, w2.y, d2.y); d2.z = fmaf(az, w2.z, d2.z); d2.w = fmaf(az, w2.w, d2.w);
            d2.x = fmaf(aw, w3.x, d2.x); d2.y = fmaf(aw, w3.y, d2.y); d2.z = fmaf(aw, w3.z, d2.z); d2.w = fmaf(aw, w3.w, d2.w);
        }
        float4 s2v = *(const float4*)&sc2[glane * 4];
        float4 h2v = *(const float4*)&sh2[glane * 4];
        float4 z2;
        z2.x = fmaxf(fmaf(d2.x, s2v.x, h2v.x), 0.f);
        z2.y = fmaxf(fmaf(d2.y, s2v.y, h2v.y), 0.f);
        z2.z = fmaxf(fmaf(d2.z, s2v.z, h2v.z), 0.f);
        z2.w = fmaxf(fmaf(d2.w, s2v.w, h2v.w), 0.f);

        if (valid) {
            ((float4*)(h_out + (size_t)n * HH))[glane] = z2;
            int b = batch[n];
            float* pp = &pooled[(size_t)b * (LL * HH) + layer * HH + glane * 4];
            atomicAdd(pp + 0, z2.x);
            atomicAdd(pp + 1, z2.y);
            atomicAdd(pp + 2, z2.z);
            atomicAdd(pp + 3, z2.w);
        }
    }
}

// ---------------------------------------------------------------------------
// Final MLP: relu(pooled @ lin1 + b1) @ lin2 + b2. One block per graph.
// ---------------------------------------------------------------------------
__global__ __launch_bounds__(64) void k_mlp(const float* __restrict__ pooled,
                                            const float* __restrict__ w1, const float* __restrict__ b1,
                                            const float* __restrict__ w2, const float* __restrict__ b2,
                                            float* __restrict__ out)
{
    int g = blockIdx.x, c = threadIdx.x;
    __shared__ float hh[64];
    float acc = b1[c];
    const float* p = pooled + g * (LL * HH);
    #pragma unroll 8
    for (int k = 0; k < LL * HH; ++k) acc = fmaf(p[k], w1[k * HH + c], acc);
    hh[c] = fmaxf(acc, 0.f);
    __syncthreads();
    if (c < CC) {
        float o = b2[c];
        #pragma unroll
        for (int k = 0; k < HH; ++k) o = fmaf(hh[k], w2[k * CC + c], o);
        out[g * CC + c] = o;
    }
}

// ---------------------------------------------------------------------------
extern "C" void kernel_launch(void* const* d_in, const int* in_sizes, int n_in,
                              void* d_out, int out_size, void* d_ws, size_t ws_size,
                              hipStream_t stream) {
    const float* x    = (const float*)d_in[0];
    const int*   ei   = (const int*)d_in[1];
    const int*   bat  = (const int*)d_in[2];
    const float* cW1  = (const float*)d_in[3];
    const float* cb1  = (const float*)d_in[4];
    const float* g1   = (const float*)d_in[5];
    const float* bb1  = (const float*)d_in[6];
    const float* m1   = (const float*)d_in[7];
    const float* v1   = (const float*)d_in[8];
    const float* cW2  = (const float*)d_in[9];
    const float* cb2  = (const float*)d_in[10];
    const float* g2   = (const float*)d_in[11];
    const float* bb2  = (const float*)d_in[12];
    const float* m2   = (const float*)d_in[13];
    const float* v2   = (const float*)d_in[14];
    const float* l1W  = (const float*)d_in[15];
    const float* l1b  = (const float*)d_in[16];
    const float* l2W  = (const float*)d_in[17];
    const float* l2b  = (const float*)d_in[18];

    const int* srcp = ei;            // edge_index[0]
    const int* dstp = ei + NE;       // edge_index[1]

    char* ws = (char*)d_ws;
    size_t off = 0;
    auto alloc = [&](size_t bytes) -> char* {
        char* p = ws + off;
        off += (bytes + 255) & ~size_t(255);
        return p;
    };
    float* h0      = (float*)alloc((size_t)NN * HH * sizeof(float));
    float* h1      = (float*)alloc((size_t)NN * HH * sizeof(float));
    float* pooled  = (float*)alloc((size_t)GG * LL * HH * sizeof(float));
    int*   row_ptr = (int*)alloc((size_t)(NN + 1) * sizeof(int));
    int*   deg     = (int*)alloc((size_t)NN * sizeof(int));
    int*   cursor  = (int*)alloc((size_t)NN * sizeof(int));
    int*   colx    = (int*)alloc((size_t)NE * sizeof(int));

    hipMemsetAsync(deg, 0, (size_t)NN * sizeof(int), stream);
    hipMemsetAsync(cursor, 0, (size_t)NN * sizeof(int), stream);
    hipMemsetAsync(pooled, 0, (size_t)GG * LL * HH * sizeof(float), stream);

    k_hist<<<(NE + 255) / 256, 256, 0, stream>>>(dstp, deg);
    k_scan<<<1, 1024, 0, stream>>>(deg, row_ptr);
    k_scatter<<<(NE + 255) / 256, 256, 0, stream>>>(srcp, dstp, row_ptr, cursor, colx);

    const float* hin = x;
    float* bufs[2] = { h0, h1 };
    const int LBLK = (NN + 15) / 16;   // 3125 blocks, 16 nodes/block
    for (int l = 0; l < LL; ++l) {
        float* hout = bufs[l & 1];
        k_layer<<<LBLK, 256, 0, stream>>>(hin, hout, row_ptr, colx, bat,
            cW1 + (size_t)l * HH * HH, cb1 + l * HH,
            g1 + l * HH, bb1 + l * HH, m1 + l * HH, v1 + l * HH,
            cW2 + (size_t)l * HH * HH, cb2 + l * HH,
            g2 + l * HH, bb2 + l * HH, m2 + l * HH, v2 + l * HH,
            pooled, l);
        hin = hout;
    }

    k_mlp<<<GG, 64, 0, stream>>>(pooled, l1W, l1b, l2W, l2b, (float*)d_out);
}

// Round 5
// 893.549 us; speedup vs baseline: 2.3222x; 2.3222x over previous
//
#include <hip/hip_runtime.h>

// Problem constants (from reference)
#define NN 50000
#define NE 800000
#define HH 64
#define LL 4
#define GG 500
#define CC 10
#define BN_EPS 1e-5f

// ---------------------------------------------------------------------------
// CSR build: histogram of dst, exclusive scan, scatter src ids.
// ---------------------------------------------------------------------------
__global__ __launch_bounds__(256) void k_hist(const int* __restrict__ dst, int* __restrict__ deg) {
    int e = blockIdx.x * 256 + threadIdx.x;
    if (e < NE) atomicAdd(&deg[dst[e]], 1);
}

__global__ __launch_bounds__(1024) void k_scan(const int* __restrict__ deg, int* __restrict__ row_ptr) {
    __shared__ int sums[1024];
    int tid = threadIdx.x;
    const int chunk = (NN + 1023) / 1024;   // 49
    int start = tid * chunk;
    int end = start + chunk;
    if (start > NN) start = NN;
    if (end > NN) end = NN;
    int s = 0;
    for (int i = start; i < end; ++i) s += deg[i];
    sums[tid] = s;
    __syncthreads();
    for (int off = 1; off < 1024; off <<= 1) {
        int v = 0;
        if (tid >= off) v = sums[tid - off];
        __syncthreads();
        if (tid >= off) sums[tid] += v;
        __syncthreads();
    }
    int run = (tid == 0) ? 0 : sums[tid - 1];
    for (int i = start; i < end; ++i) { row_ptr[i] = run; run += deg[i]; }
    if (tid == 1023) row_ptr[NN] = sums[1023];
}

__global__ __launch_bounds__(256) void k_scatter(const int* __restrict__ src, const int* __restrict__ dst,
                                                 const int* __restrict__ row_ptr, int* __restrict__ cursor,
                                                 int* __restrict__ col) {
    int e = blockIdx.x * 256 + threadIdx.x;
    if (e < NE) {
        int d = dst[e];
        int pos = atomicAdd(&cursor[d], 1);
        col[row_ptr[d] + pos] = src[e];
    }
}

// ---------------------------------------------------------------------------
// Fused GIN layer, 4 nodes per wave. NO occupancy bound (R2 spilled at 64 VGPR).
//   16-lane group per node; lane holds float4 (4 features). Gather with x4
//   unroll (up to 16 row-loads in flight per wave), GEMMs via width-16 shfl
//   broadcast + float4 LDS weight reads, BN+ReLU folded. No atomics.
// ---------------------------------------------------------------------------
__global__ __launch_bounds__(256) void k_layer(
    const float* __restrict__ h_in, float* __restrict__ h_out,
    const int* __restrict__ row_ptr, const int* __restrict__ col,
    const float* __restrict__ W1, const float* __restrict__ lb1,
    const float* __restrict__ g1, const float* __restrict__ bb1,
    const float* __restrict__ m1, const float* __restrict__ v1,
    const float* __restrict__ W2, const float* __restrict__ lb2,
    const float* __restrict__ g2, const float* __restrict__ bb2,
    const float* __restrict__ m2, const float* __restrict__ v2)
{
    __shared__ float W1s[64 * 64];
    __shared__ float W2s[64 * 64];
    __shared__ float sc1[64], sh1[64], sc2[64], sh2[64];
    int tid = threadIdx.x;
    {
        const float4* a = (const float4*)W1;
        const float4* b = (const float4*)W2;
        float4* A = (float4*)W1s;
        float4* B = (float4*)W2s;
        for (int i = tid; i < 1024; i += 256) { A[i] = a[i]; B[i] = b[i]; }
    }
    if (tid < 64) {
        float s1 = g1[tid] * rsqrtf(v1[tid] + BN_EPS);
        sc1[tid] = s1;
        sh1[tid] = (lb1[tid] - m1[tid]) * s1 + bb1[tid];
        float s2 = g2[tid] * rsqrtf(v2[tid] + BN_EPS);
        sc2[tid] = s2;
        sh2[tid] = (lb2[tid] - m2[tid]) * s2 + bb2[tid];
    }
    __syncthreads();

    int lane  = tid & 63;
    int wave  = tid >> 6;
    int glane = lane & 15;   // lane within 16-group
    int grp   = lane >> 4;   // group (node slot) within wave

    // NN = 50000 is divisible by 16, so every n in range is valid.
    for (int nb = blockIdx.x * 16 + wave * 4; nb < NN; nb += gridDim.x * 16) {
        int n = nb + grp;
        float4 acc = ((const float4*)(h_in + (size_t)n * HH))[glane];
        int j = row_ptr[n];
        int fin = row_ptr[n + 1];
        float4 acc2 = make_float4(0.f, 0.f, 0.f, 0.f);
        for (; j + 4 <= fin; j += 4) {
            int s0 = col[j], s1i = col[j + 1], s2i = col[j + 2], s3i = col[j + 3];
            float4 v0 = ((const float4*)(h_in + (size_t)s0  * HH))[glane];
            float4 va = ((const float4*)(h_in + (size_t)s1i * HH))[glane];
            float4 vb = ((const float4*)(h_in + (size_t)s2i * HH))[glane];
            float4 vc = ((const float4*)(h_in + (size_t)s3i * HH))[glane];
            acc.x  += v0.x + vb.x;  acc.y  += v0.y + vb.y;
            acc.z  += v0.z + vb.z;  acc.w  += v0.w + vb.w;
            acc2.x += va.x + vc.x;  acc2.y += va.y + vc.y;
            acc2.z += va.z + vc.z;  acc2.w += va.w + vc.w;
        }
        for (; j < fin; ++j) {
            int s0 = col[j];
            float4 v0 = ((const float4*)(h_in + (size_t)s0 * HH))[glane];
            acc.x += v0.x; acc.y += v0.y; acc.z += v0.z; acc.w += v0.w;
        }
        acc.x += acc2.x; acc.y += acc2.y; acc.z += acc2.z; acc.w += acc2.w;

        // ---- GEMM1 (+BN1+ReLU): lane computes c = glane*4 .. glane*4+3
        float4 d = make_float4(0.f, 0.f, 0.f, 0.f);
        #pragma unroll
        for (int kl = 0; kl < 16; ++kl) {
            float ax = __shfl(acc.x, kl, 16);
            float ay = __shfl(acc.y, kl, 16);
            float az = __shfl(acc.z, kl, 16);
            float aw = __shfl(acc.w, kl, 16);
            float4 w0 = *(const float4*)&W1s[(kl * 4 + 0) * HH + glane * 4];
            float4 w1 = *(const float4*)&W1s[(kl * 4 + 1) * HH + glane * 4];
            float4 w2 = *(const float4*)&W1s[(kl * 4 + 2) * HH + glane * 4];
            float4 w3 = *(const float4*)&W1s[(kl * 4 + 3) * HH + glane * 4];
            d.x = fmaf(ax, w0.x, d.x); d.y = fmaf(ax, w0.y, d.y); d.z = fmaf(ax, w0.z, d.z); d.w = fmaf(ax, w0.w, d.w);
            d.x = fmaf(ay, w1.x, d.x); d.y = fmaf(ay, w1.y, d.y); d.z = fmaf(ay, w1.z, d.z); d.w = fmaf(ay, w1.w, d.w);
            d.x = fmaf(az, w2.x, d.x); d.y = fmaf(az, w2.y, d.y); d.z = fmaf(az, w2.z, d.z); d.w = fmaf(az, w2.w, d.w);
            d.x = fmaf(aw, w3.x, d.x); d.y = fmaf(aw, w3.y, d.y); d.z = fmaf(aw, w3.z, d.z); d.w = fmaf(aw, w3.w, d.w);
        }
        float4 s1v = *(const float4*)&sc1[glane * 4];
        float4 h1v = *(const float4*)&sh1[glane * 4];
        float4 z;
        z.x = fmaxf(fmaf(d.x, s1v.x, h1v.x), 0.f);
        z.y = fmaxf(fmaf(d.y, s1v.y, h1v.y), 0.f);
        z.z = fmaxf(fmaf(d.z, s1v.z, h1v.z), 0.f);
        z.w = fmaxf(fmaf(d.w, s1v.w, h1v.w), 0.f);

        // ---- GEMM2 (+BN2+ReLU)
        float4 d2 = make_float4(0.f, 0.f, 0.f, 0.f);
        #pragma unroll
        for (int kl = 0; kl < 16; ++kl) {
            float ax = __shfl(z.x, kl, 16);
            float ay = __shfl(z.y, kl, 16);
            float az = __shfl(z.z, kl, 16);
            float aw = __shfl(z.w, kl, 16);
            float4 w0 = *(const float4*)&W2s[(kl * 4 + 0) * HH + glane * 4];
            float4 w1 = *(const float4*)&W2s[(kl * 4 + 1) * HH + glane * 4];
            float4 w2 = *(const float4*)&W2s[(kl * 4 + 2) * HH + glane * 4];
            float4 w3 = *(const float4*)&W2s[(kl * 4 + 3) * HH + glane * 4];
            d2.x = fmaf(ax, w0.x, d2.x); d2.y = fmaf(ax, w0.y, d2.y); d2.z = fmaf(ax, w0.z, d2.z); d2.w = fmaf(ax, w0.w, d2.w);
            d2.x = fmaf(ay, w1.x, d2.x); d2.y = fmaf(ay, w1.y, d2.y); d2.z = fmaf(ay, w1.z, d2.z); d2.w = fmaf(ay, w1.w, d2.w);
            d2.x = fmaf(az, w2.x, d2.x); d2.y = fmaf(az, w2.y, d2.y); d2.z = fmaf(az, w2.z, d2.z); d2.w = fmaf(az, w2.w, d2.w);
            d2.x = fmaf(aw, w3.x, d2.x); d2.y = fmaf(aw, w3.y, d2.y); d2.z = fmaf(aw, w3.z, d2.z); d2.w = fmaf(aw, w3.w, d2.w);
        }
        float4 s2v = *(const float4*)&sc2[glane * 4];
        float4 h2v = *(const float4*)&sh2[glane * 4];
        float4 z2;
        z2.x = fmaxf(fmaf(d2.x, s2v.x, h2v.x), 0.f);
        z2.y = fmaxf(fmaf(d2.y, s2v.y, h2v.y), 0.f);
        z2.z = fmaxf(fmaf(d2.z, s2v.z, h2v.z), 0.f);
        z2.w = fmaxf(fmaf(d2.w, s2v.w, h2v.w), 0.f);

        ((float4*)(h_out + (size_t)n * HH))[glane] = z2;
    }
}

// ---------------------------------------------------------------------------
// Segment-sum pooling per layer (batch is sorted — no atomics).
// Block g: binary-search node range of graph g, 4 quarter-wave partial sums
// over contiguous rows, LDS reduce, single store of 64 floats.
// ---------------------------------------------------------------------------
__global__ __launch_bounds__(256) void k_pool(const float* __restrict__ h,
                                              const int* __restrict__ batch,
                                              float* __restrict__ pooled, int layer)
{
    int g = blockIdx.x;
    int t = threadIdx.x;
    int c = t & 63;
    int q = t >> 6;
    int lo = 0, hi = NN;
    while (lo < hi) { int mid = (lo + hi) >> 1; if (batch[mid] < g) lo = mid + 1; else hi = mid; }
    int s = lo;
    hi = NN;
    while (lo < hi) { int mid = (lo + hi) >> 1; if (batch[mid] < g + 1) lo = mid + 1; else hi = mid; }
    int e = lo;
    float acc = 0.f;
    for (int n = s + q; n < e; n += 4) acc += h[(size_t)n * HH + c];
    __shared__ float red[256];
    red[t] = acc;
    __syncthreads();
    if (t < 64)
        pooled[(size_t)g * (LL * HH) + layer * HH + c] = red[c] + red[64 + c] + red[128 + c] + red[192 + c];
}

// ---------------------------------------------------------------------------
// Final MLP: relu(pooled @ lin1 + b1) @ lin2 + b2. One block per graph.
// ---------------------------------------------------------------------------
__global__ __launch_bounds__(64) void k_mlp(const float* __restrict__ pooled,
                                            const float* __restrict__ w1, const float* __restrict__ b1,
                                            const float* __restrict__ w2, const float* __restrict__ b2,
                                            float* __restrict__ out)
{
    int g = blockIdx.x, c = threadIdx.x;
    __shared__ float hh[64];
    float acc = b1[c];
    const float* p = pooled + g * (LL * HH);
    #pragma unroll 8
    for (int k = 0; k < LL * HH; ++k) acc = fmaf(p[k], w1[k * HH + c], acc);
    hh[c] = fmaxf(acc, 0.f);
    __syncthreads();
    if (c < CC) {
        float o = b2[c];
        #pragma unroll
        for (int k = 0; k < HH; ++k) o = fmaf(hh[k], w2[k * CC + c], o);
        out[g * CC + c] = o;
    }
}

// ---------------------------------------------------------------------------
extern "C" void kernel_launch(void* const* d_in, const int* in_sizes, int n_in,
                              void* d_out, int out_size, void* d_ws, size_t ws_size,
                              hipStream_t stream) {
    const float* x    = (const float*)d_in[0];
    const int*   ei   = (const int*)d_in[1];
    const int*   bat  = (const int*)d_in[2];
    const float* cW1  = (const float*)d_in[3];
    const float* cb1  = (const float*)d_in[4];
    const float* g1   = (const float*)d_in[5];
    const float* bb1  = (const float*)d_in[6];
    const float* m1   = (const float*)d_in[7];
    const float* v1   = (const float*)d_in[8];
    const float* cW2  = (const float*)d_in[9];
    const float* cb2  = (const float*)d_in[10];
    const float* g2   = (const float*)d_in[11];
    const float* bb2  = (const float*)d_in[12];
    const float* m2   = (const float*)d_in[13];
    const float* v2   = (const float*)d_in[14];
    const float* l1W  = (const float*)d_in[15];
    const float* l1b  = (const float*)d_in[16];
    const float* l2W  = (const float*)d_in[17];
    const float* l2b  = (const float*)d_in[18];

    const int* srcp = ei;            // edge_index[0]
    const int* dstp = ei + NE;       // edge_index[1]

    char* ws = (char*)d_ws;
    size_t off = 0;
    auto alloc = [&](size_t bytes) -> char* {
        char* p = ws + off;
        off += (bytes + 255) & ~size_t(255);
        return p;
    };
    float* h0      = (float*)alloc((size_t)NN * HH * sizeof(float));
    float* h1      = (float*)alloc((size_t)NN * HH * sizeof(float));
    float* pooled  = (float*)alloc((size_t)GG * LL * HH * sizeof(float));
    int*   row_ptr = (int*)alloc((size_t)(NN + 1) * sizeof(int));
    int*   deg     = (int*)alloc((size_t)NN * sizeof(int));
    int*   cursor  = (int*)alloc((size_t)NN * sizeof(int));
    int*   colx    = (int*)alloc((size_t)NE * sizeof(int));

    hipMemsetAsync(deg, 0, (size_t)NN * sizeof(int), stream);
    hipMemsetAsync(cursor, 0, (size_t)NN * sizeof(int), stream);

    k_hist<<<(NE + 255) / 256, 256, 0, stream>>>(dstp, deg);
    k_scan<<<1, 1024, 0, stream>>>(deg, row_ptr);
    k_scatter<<<(NE + 255) / 256, 256, 0, stream>>>(srcp, dstp, row_ptr, cursor, colx);

    const float* hin = x;
    float* bufs[2] = { h0, h1 };
    for (int l = 0; l < LL; ++l) {
        float* hout = bufs[l & 1];
        k_layer<<<1024, 256, 0, stream>>>(hin, hout, row_ptr, colx,
            cW1 + (size_t)l * HH * HH, cb1 + l * HH,
            g1 + l * HH, bb1 + l * HH, m1 + l * HH, v1 + l * HH,
            cW2 + (size_t)l * HH * HH, cb2 + l * HH,
            g2 + l * HH, bb2 + l * HH, m2 + l * HH, v2 + l * HH);
        k_pool<<<GG, 256, 0, stream>>>(hout, bat, pooled, l);
        hin = hout;
    }

    k_mlp<<<GG, 64, 0, stream>>>(pooled, l1W, l1b, l2W, l2b, (float*)d_out);
}

// Round 7
// 512.156 us; speedup vs baseline: 4.0515x; 1.7447x over previous
//
#include <hip/hip_runtime.h>

// Problem constants (from reference)
#define NN 50000
#define NE 800000
#define HH 64
#define LL 4
#define GG 500
#define CC 10
#define BN_EPS 1e-5f

// ---------------------------------------------------------------------------
// CSR build: histogram of dst, exclusive scan, scatter src ids.
// ---------------------------------------------------------------------------
__global__ __launch_bounds__(256) void k_hist(const int* __restrict__ dst, int* __restrict__ deg) {
    int e = blockIdx.x * 256 + threadIdx.x;
    if (e < NE) atomicAdd(&deg[dst[e]], 1);
}

__global__ __launch_bounds__(1024) void k_scan(const int* __restrict__ deg, int* __restrict__ row_ptr) {
    __shared__ int sums[1024];
    int tid = threadIdx.x;
    const int chunk = (NN + 1023) / 1024;   // 49
    int start = tid * chunk;
    int end = start + chunk;
    if (start > NN) start = NN;
    if (end > NN) end = NN;
    int s = 0;
    for (int i = start; i < end; ++i) s += deg[i];
    sums[tid] = s;
    __syncthreads();
    for (int off = 1; off < 1024; off <<= 1) {
        int v = 0;
        if (tid >= off) v = sums[tid - off];
        __syncthreads();
        if (tid >= off) sums[tid] += v;
        __syncthreads();
    }
    int run = (tid == 0) ? 0 : sums[tid - 1];
    for (int i = start; i < end; ++i) { row_ptr[i] = run; run += deg[i]; }
    if (tid == 1023) row_ptr[NN] = sums[1023];
}

__global__ __launch_bounds__(256) void k_scatter(const int* __restrict__ src, const int* __restrict__ dst,
                                                 const int* __restrict__ row_ptr, int* __restrict__ cursor,
                                                 int* __restrict__ col) {
    int e = blockIdx.x * 256 + threadIdx.x;
    if (e < NE) {
        int d = dst[e];
        int pos = atomicAdd(&cursor[d], 1);
        col[row_ptr[d] + pos] = src[e];
    }
}

// ---------------------------------------------------------------------------
// Aggregation only: agg[n] = h[n] + sum_{j->n} h[j].
// No LDS, one node-quad per wave (12500 independent waves), 16-lane group per
// node, float4 per lane, x4 edge unroll -> max memory-level parallelism.
// ---------------------------------------------------------------------------
__global__ __launch_bounds__(256) void k_agg(
    const float* __restrict__ h_in, float* __restrict__ agg,
    const int* __restrict__ row_ptr, const int* __restrict__ col)
{
    int tid   = threadIdx.x;
    int lane  = tid & 63;
    int wave  = tid >> 6;
    int glane = lane & 15;
    int grp   = lane >> 4;
    int n = blockIdx.x * 16 + wave * 4 + grp;   // 3125*16 = 50000 exactly

    float4 acc = ((const float4*)(h_in + (size_t)n * HH))[glane];
    int j = row_ptr[n];
    int fin = row_ptr[n + 1];
    float4 acc2 = make_float4(0.f, 0.f, 0.f, 0.f);
    for (; j + 4 <= fin; j += 4) {
        int s0 = col[j], s1i = col[j + 1], s2i = col[j + 2], s3i = col[j + 3];
        float4 v0 = ((const float4*)(h_in + (size_t)s0  * HH))[glane];
        float4 va = ((const float4*)(h_in + (size_t)s1i * HH))[glane];
        float4 vb = ((const float4*)(h_in + (size_t)s2i * HH))[glane];
        float4 vc = ((const float4*)(h_in + (size_t)s3i * HH))[glane];
        acc.x  += v0.x + vb.x;  acc.y  += v0.y + vb.y;
        acc.z  += v0.z + vb.z;  acc.w  += v0.w + vb.w;
        acc2.x += va.x + vc.x;  acc2.y += va.y + vc.y;
        acc2.z += va.z + vc.z;  acc2.w += va.w + vc.w;
    }
    for (; j < fin; ++j) {
        int s0 = col[j];
        float4 v0 = ((const float4*)(h_in + (size_t)s0 * HH))[glane];
        acc.x += v0.x; acc.y += v0.y; acc.z += v0.z; acc.w += v0.w;
    }
    acc.x += acc2.x; acc.y += acc2.y; acc.z += acc2.z; acc.w += acc2.w;

    ((float4*)(agg + (size_t)n * HH))[glane] = acc;
}

// ---------------------------------------------------------------------------
// Dense MLP for one layer: h_out = relu(bn2(relu(bn1(agg@W1))@W2)).
// 128-node tile per block. agg tile in LDS ([128][68] padded), one 16KB
// weight buffer staged W1 then W2. Thread: 8 rows x 4 cols register block;
// float4 LDS reads amortized over 4 k-steps -> VALU-bound.
// ---------------------------------------------------------------------------
#define MT 128
#define SAP 68   // padded row stride (floats): 16B-aligned, bank-staggered

__global__ __launch_bounds__(256) void k_mlp2(
    const float* __restrict__ agg, float* __restrict__ h_out,
    const float* __restrict__ W1, const float* __restrict__ lb1,
    const float* __restrict__ g1, const float* __restrict__ bb1,
    const float* __restrict__ m1, const float* __restrict__ v1,
    const float* __restrict__ W2, const float* __restrict__ lb2,
    const float* __restrict__ g2, const float* __restrict__ bb2,
    const float* __restrict__ m2, const float* __restrict__ v2)
{
    __shared__ float sW[64 * 64];     // 16 KB, reused W1 then W2
    __shared__ float sA[MT * SAP];    // 34.8 KB

    int tid = threadIdx.x;
    int c0  = (tid & 15) * 4;         // 4 output cols
    int rt  = tid >> 4;               // row-thread 0..15; rows rt+16*i
    int base = blockIdx.x * MT;

    // BN+bias folded constants for this thread's 4 columns (both layers)
    float sc1v[4], sh1v[4], sc2v[4], sh2v[4];
    #pragma unroll
    for (int i = 0; i < 4; ++i) {
        int c = c0 + i;
        float s1 = g1[c] * rsqrtf(v1[c] + BN_EPS);
        sc1v[i] = s1;
        sh1v[i] = (lb1[c] - m1[c]) * s1 + bb1[c];
        float s2 = g2[c] * rsqrtf(v2[c] + BN_EPS);
        sc2v[i] = s2;
        sh2v[i] = (lb2[c] - m2[c]) * s2 + bb2[c];
    }

    // stage W1 + agg tile
    for (int i = tid; i < 1024; i += 256)
        ((float4*)sW)[i] = ((const float4*)W1)[i];
    for (int i = tid; i < MT * 16; i += 256) {
        int r = i >> 4, cq = i & 15;
        int gr = base + r;
        float4 v = (gr < NN) ? ((const float4*)(agg + (size_t)gr * HH))[cq]
                             : make_float4(0.f, 0.f, 0.f, 0.f);
        *(float4*)&sA[r * SAP + cq * 4] = v;
    }
    __syncthreads();

    // ---- GEMM1
    float acc1[8][4];
    #pragma unroll
    for (int i = 0; i < 8; ++i) { acc1[i][0]=0.f; acc1[i][1]=0.f; acc1[i][2]=0.f; acc1[i][3]=0.f; }
    for (int k4 = 0; k4 < 16; ++k4) {
        float4 a[8];
        #pragma unroll
        for (int i = 0; i < 8; ++i)
            a[i] = *(const float4*)&sA[(rt + 16 * i) * SAP + k4 * 4];
        #pragma unroll
        for (int kk = 0; kk < 4; ++kk) {
            float4 w = *(const float4*)&sW[(k4 * 4 + kk) * 64 + c0];
            #pragma unroll
            for (int i = 0; i < 8; ++i) {
                float av = (&a[i].x)[kk];
                acc1[i][0] = fmaf(av, w.x, acc1[i][0]);
                acc1[i][1] = fmaf(av, w.y, acc1[i][1]);
                acc1[i][2] = fmaf(av, w.z, acc1[i][2]);
                acc1[i][3] = fmaf(av, w.w, acc1[i][3]);
            }
        }
    }
    __syncthreads();   // GEMM1 reads of sA/sW complete

    // z = relu(bn1(.)) -> back into sA ; stage W2
    #pragma unroll
    for (int i = 0; i < 8; ++i) {
        float4 z;
        z.x = fmaxf(fmaf(acc1[i][0], sc1v[0], sh1v[0]), 0.f);
        z.y = fmaxf(fmaf(acc1[i][1], sc1v[1], sh1v[1]), 0.f);
        z.z = fmaxf(fmaf(acc1[i][2], sc1v[2], sh1v[2]), 0.f);
        z.w = fmaxf(fmaf(acc1[i][3], sc1v[3], sh1v[3]), 0.f);
        *(float4*)&sA[(rt + 16 * i) * SAP + c0] = z;
    }
    for (int i = tid; i < 1024; i += 256)
        ((float4*)sW)[i] = ((const float4*)W2)[i];
    __syncthreads();

    // ---- GEMM2
    float acc2[8][4];
    #pragma unroll
    for (int i = 0; i < 8; ++i) { acc2[i][0]=0.f; acc2[i][1]=0.f; acc2[i][2]=0.f; acc2[i][3]=0.f; }
    for (int k4 = 0; k4 < 16; ++k4) {
        float4 a[8];
        #pragma unroll
        for (int i = 0; i < 8; ++i)
            a[i] = *(const float4*)&sA[(rt + 16 * i) * SAP + k4 * 4];
        #pragma unroll
        for (int kk = 0; kk < 4; ++kk) {
            float4 w = *(const float4*)&sW[(k4 * 4 + kk) * 64 + c0];
            #pragma unroll
            for (int i = 0; i < 8; ++i) {
                float av = (&a[i].x)[kk];
                acc2[i][0] = fmaf(av, w.x, acc2[i][0]);
                acc2[i][1] = fmaf(av, w.y, acc2[i][1]);
                acc2[i][2] = fmaf(av, w.z, acc2[i][2]);
                acc2[i][3] = fmaf(av, w.w, acc2[i][3]);
            }
        }
    }

    // epilogue: bn2 + relu, store
    #pragma unroll
    for (int i = 0; i < 8; ++i) {
        int gr = base + rt + 16 * i;
        if (gr < NN) {
            float4 z;
            z.x = fmaxf(fmaf(acc2[i][0], sc2v[0], sh2v[0]), 0.f);
            z.y = fmaxf(fmaf(acc2[i][1], sc2v[1], sh2v[1]), 0.f);
            z.z = fmaxf(fmaf(acc2[i][2], sc2v[2], sh2v[2]), 0.f);
            z.w = fmaxf(fmaf(acc2[i][3], sc2v[3], sh2v[3]), 0.f);
            *(float4*)&h_out[(size_t)gr * HH + c0] = z;
        }
    }
}

// ---------------------------------------------------------------------------
// Segment-sum pooling per layer (batch is sorted — no atomics).
// ---------------------------------------------------------------------------
__global__ __launch_bounds__(256) void k_pool(const float* __restrict__ h,
                                              const int* __restrict__ batch,
                                              float* __restrict__ pooled, int layer)
{
    int g = blockIdx.x;
    int t = threadIdx.x;
    int c = t & 63;
    int q = t >> 6;
    int lo = 0, hi = NN;
    while (lo < hi) { int mid = (lo + hi) >> 1; if (batch[mid] < g) lo = mid + 1; else hi = mid; }
    int s = lo;
    hi = NN;
    while (lo < hi) { int mid = (lo + hi) >> 1; if (batch[mid] < g + 1) lo = mid + 1; else hi = mid; }
    int e = lo;
    float acc = 0.f;
    for (int n = s + q; n < e; n += 4) acc += h[(size_t)n * HH + c];
    __shared__ float red[256];
    red[t] = acc;
    __syncthreads();
    if (t < 64)
        pooled[(size_t)g * (LL * HH) + layer * HH + c] = red[c] + red[64 + c] + red[128 + c] + red[192 + c];
}

// ---------------------------------------------------------------------------
// Final MLP: relu(pooled @ lin1 + b1) @ lin2 + b2. One block per graph.
// ---------------------------------------------------------------------------
__global__ __launch_bounds__(64) void k_mlp(const float* __restrict__ pooled,
                                            const float* __restrict__ w1, const float* __restrict__ b1,
                                            const float* __restrict__ w2, const float* __restrict__ b2,
                                            float* __restrict__ out)
{
    int g = blockIdx.x, c = threadIdx.x;
    __shared__ float hh[64];
    float acc = b1[c];
    const float* p = pooled + g * (LL * HH);
    #pragma unroll 8
    for (int k = 0; k < LL * HH; ++k) acc = fmaf(p[k], w1[k * HH + c], acc);
    hh[c] = fmaxf(acc, 0.f);
    __syncthreads();
    if (c < CC) {
        float o = b2[c];
        #pragma unroll
        for (int k = 0; k < HH; ++k) o = fmaf(hh[k], w2[k * CC + c], o);
        out[g * CC + c] = o;
    }
}

// ---------------------------------------------------------------------------
extern "C" void kernel_launch(void* const* d_in, const int* in_sizes, int n_in,
                              void* d_out, int out_size, void* d_ws, size_t ws_size,
                              hipStream_t stream) {
    const float* x    = (const float*)d_in[0];
    const int*   ei   = (const int*)d_in[1];
    const int*   bat  = (const int*)d_in[2];
    const float* cW1  = (const float*)d_in[3];
    const float* cb1  = (const float*)d_in[4];
    const float* g1   = (const float*)d_in[5];
    const float* bb1  = (const float*)d_in[6];
    const float* m1   = (const float*)d_in[7];
    const float* v1   = (const float*)d_in[8];
    const float* cW2  = (const float*)d_in[9];
    const float* cb2  = (const float*)d_in[10];
    const float* g2   = (const float*)d_in[11];
    const float* bb2  = (const float*)d_in[12];
    const float* m2   = (const float*)d_in[13];
    const float* v2   = (const float*)d_in[14];
    const float* l1W  = (const float*)d_in[15];
    const float* l1b  = (const float*)d_in[16];
    const float* l2W  = (const float*)d_in[17];
    const float* l2b  = (const float*)d_in[18];

    const int* srcp = ei;            // edge_index[0]
    const int* dstp = ei + NE;       // edge_index[1]

    char* ws = (char*)d_ws;
    size_t off = 0;
    auto alloc = [&](size_t bytes) -> char* {
        char* p = ws + off;
        off += (bytes + 255) & ~size_t(255);
        return p;
    };
    float* h0      = (float*)alloc((size_t)NN * HH * sizeof(float));
    float* h1      = (float*)alloc((size_t)NN * HH * sizeof(float));
    float* aggb    = (float*)alloc((size_t)NN * HH * sizeof(float));
    float* pooled  = (float*)alloc((size_t)GG * LL * HH * sizeof(float));
    int*   row_ptr = (int*)alloc((size_t)(NN + 1) * sizeof(int));
    int*   deg     = (int*)alloc((size_t)NN * sizeof(int));
    int*   cursor  = (int*)alloc((size_t)NN * sizeof(int));
    int*   colx    = (int*)alloc((size_t)NE * sizeof(int));

    hipMemsetAsync(deg, 0, (size_t)NN * sizeof(int), stream);
    hipMemsetAsync(cursor, 0, (size_t)NN * sizeof(int), stream);

    k_hist<<<(NE + 255) / 256, 256, 0, stream>>>(dstp, deg);
    k_scan<<<1, 1024, 0, stream>>>(deg, row_ptr);
    k_scatter<<<(NE + 255) / 256, 256, 0, stream>>>(srcp, dstp, row_ptr, cursor, colx);

    const float* hin = x;
    float* bufs[2] = { h0, h1 };
    const int AGG_BLK = NN / 16;               // 3125
    const int MLP_BLK = (NN + MT - 1) / MT;    // 391
    for (int l = 0; l < LL; ++l) {
        float* hout = bufs[l & 1];
        k_agg<<<AGG_BLK, 256, 0, stream>>>(hin, aggb, row_ptr, colx);
        k_mlp2<<<MLP_BLK, 256, 0, stream>>>(aggb, hout,
            cW1 + (size_t)l * HH * HH, cb1 + l * HH,
            g1 + l * HH, bb1 + l * HH, m1 + l * HH, v1 + l * HH,
            cW2 + (size_t)l * HH * HH, cb2 + l * HH,
            g2 + l * HH, bb2 + l * HH, m2 + l * HH, v2 + l * HH);
        k_pool<<<GG, 256, 0, stream>>>(hout, bat, pooled, l);
        hin = hout;
    }

    k_mlp<<<GG, 64, 0, stream>>>(pooled, l1W, l1b, l2W, l2b, (float*)d_out);
}

// Round 9
// 405.617 us; speedup vs baseline: 5.1157x; 1.2627x over previous
//
#include <hip/hip_runtime.h>

// Problem constants (from reference)
#define NN 50000
#define NE 800000
#define HH 64
#define LL 4
#define GG 500
#define CC 10
#define BN_EPS 1e-5f
#define SCB 200   // scan blocks (200*256 = 51200 >= 50000)

// ---- bf16 helpers (storage-only precision cut; math stays fp32) ----
__device__ inline float bf2f(unsigned short u) {
    union { unsigned int i; float f; } v; v.i = ((unsigned int)u) << 16; return v.f;
}
__device__ inline unsigned short f2bf(float f) {
    union { float f; unsigned int i; } v; v.f = f;
    unsigned int u = v.i + 0x7fffu + ((v.i >> 16) & 1u);   // round-nearest-even
    return (unsigned short)(u >> 16);
}
__device__ inline void addrow8(float* acc, uint4 u) {
    #pragma unroll
    for (int q = 0; q < 4; ++q) {
        unsigned int w = (&u.x)[q];
        union { unsigned int i; float f; } lo, hi;
        lo.i = w << 16; hi.i = w & 0xffff0000u;
        acc[2 * q]     += lo.f;
        acc[2 * q + 1] += hi.f;
    }
}

// ---------------------------------------------------------------------------
// x (fp32) -> bf16 table for the gather path
// ---------------------------------------------------------------------------
__global__ __launch_bounds__(256) void k_cast(const float* __restrict__ x, unsigned short* __restrict__ xb) {
    int i = blockIdx.x * 256 + threadIdx.x;   // 3125*256 = 800000 float4 groups
    if (i < NN * 16) {
        float4 v = ((const float4*)x)[i];
        uint2 p;
        p.x = (unsigned int)f2bf(v.x) | ((unsigned int)f2bf(v.y) << 16);
        p.y = (unsigned int)f2bf(v.z) | ((unsigned int)f2bf(v.w) << 16);
        ((uint2*)xb)[i] = p;
    }
}

// ---------------------------------------------------------------------------
// CSR build: histogram, hierarchical scan (3 small kernels), scatter.
// ---------------------------------------------------------------------------
__global__ __launch_bounds__(256) void k_hist(const int* __restrict__ dst, int* __restrict__ deg) {
    int e = blockIdx.x * 256 + threadIdx.x;
    if (e < NE) atomicAdd(&deg[dst[e]], 1);
}

__global__ __launch_bounds__(256) void k_scan1(const int* __restrict__ deg, int* __restrict__ incl,
                                               int* __restrict__ bsum) {
    int t = threadIdx.x;
    int idx = blockIdx.x * 256 + t;
    __shared__ int s[256];
    int v = (idx < NN) ? deg[idx] : 0;
    s[t] = v;
    __syncthreads();
    for (int off = 1; off < 256; off <<= 1) {
        int u = (t >= off) ? s[t - off] : 0;
        __syncthreads();
        if (t >= off) s[t] += u;
        __syncthreads();
    }
    if (idx < NN) incl[idx] = s[t];
    if (t == 255) bsum[blockIdx.x] = s[255];
}

__global__ __launch_bounds__(256) void k_scan2(const int* __restrict__ bsum, int* __restrict__ boff,
                                               int* __restrict__ row_ptr) {
    int t = threadIdx.x;
    __shared__ int s[256];
    int v = (t < SCB) ? bsum[t] : 0;
    s[t] = v;
    __syncthreads();
    for (int off = 1; off < 256; off <<= 1) {
        int u = (t >= off) ? s[t - off] : 0;
        __syncthreads();
        if (t >= off) s[t] += u;
        __syncthreads();
    }
    if (t < SCB) boff[t] = s[t] - v;       // exclusive block offset
    if (t == 255) row_ptr[NN] = s[255];    // grand total
}

__global__ __launch_bounds__(256) void k_scan3(const int* __restrict__ deg, const int* __restrict__ incl,
                                               const int* __restrict__ boff, int* __restrict__ row_ptr) {
    int idx = blockIdx.x * 256 + threadIdx.x;
    if (idx < NN) row_ptr[idx] = incl[idx] - deg[idx] + boff[blockIdx.x];
}

__global__ __launch_bounds__(256) void k_scatter(const int* __restrict__ src, const int* __restrict__ dst,
                                                 const int* __restrict__ row_ptr, int* __restrict__ cursor,
                                                 int* __restrict__ col) {
    int e = blockIdx.x * 256 + threadIdx.x;
    if (e < NE) {
        int d = dst[e];
        int pos = atomicAdd(&cursor[d], 1);
        col[row_ptr[d] + pos] = src[e];
    }
}

// ---------------------------------------------------------------------------
// Aggregation: agg[n] = h[n] + sum_{j->n} h[j], h stored bf16, fp32 accumulate.
// 8-lane group per node (row = 128B), 8 nodes/wave, x4 edge unroll.
// ---------------------------------------------------------------------------
__global__ __launch_bounds__(256) void k_agg(
    const unsigned short* __restrict__ hb, float* __restrict__ agg,
    const int* __restrict__ row_ptr, const int* __restrict__ col)
{
    int tid  = threadIdx.x;
    int lane = tid & 63;
    int wave = tid >> 6;
    int gl   = lane & 7;    // lane within 8-group; owns features gl*8..gl*8+7
    int grp  = lane >> 3;   // node slot within wave (0..7)
    int n = blockIdx.x * 32 + wave * 8 + grp;
    if (n >= NN) return;

    const uint4* hv = (const uint4*)hb;    // 8 uint4 per 64-elem row
    float acc[8]  = {0.f, 0.f, 0.f, 0.f, 0.f, 0.f, 0.f, 0.f};
    float acc2[8] = {0.f, 0.f, 0.f, 0.f, 0.f, 0.f, 0.f, 0.f};
    addrow8(acc, hv[(size_t)n * 8 + gl]);

    int j = row_ptr[n], fin = row_ptr[n + 1];
    for (; j + 4 <= fin; j += 4) {
        int s0 = col[j], s1 = col[j + 1], s2 = col[j + 2], s3 = col[j + 3];
        uint4 u0 = hv[(size_t)s0 * 8 + gl];
        uint4 u1 = hv[(size_t)s1 * 8 + gl];
        uint4 u2 = hv[(size_t)s2 * 8 + gl];
        uint4 u3 = hv[(size_t)s3 * 8 + gl];
        addrow8(acc, u0);  addrow8(acc2, u1);
        addrow8(acc, u2);  addrow8(acc2, u3);
    }
    for (; j < fin; ++j)
        addrow8(acc, hv[(size_t)col[j] * 8 + gl]);

    #pragma unroll
    for (int q = 0; q < 8; ++q) acc[q] += acc2[q];

    float* out = agg + (size_t)n * HH + gl * 8;
    *(float4*)(out)     = make_float4(acc[0], acc[1], acc[2], acc[3]);
    *(float4*)(out + 4) = make_float4(acc[4], acc[5], acc[6], acc[7]);
}

// ---------------------------------------------------------------------------
// Dense MLP for one layer: h_out(bf16) = relu(bn2(relu(bn1(agg@W1))@W2)).
// 128-node tile, agg fp32 in padded LDS, one 16KB weight buffer (W1 then W2),
// 8x4 register blocking.
// ---------------------------------------------------------------------------
#define MT 128
#define SAP 68

__global__ __launch_bounds__(256) void k_mlp2(
    const float* __restrict__ agg, unsigned short* __restrict__ h_out,
    const float* __restrict__ W1, const float* __restrict__ lb1,
    const float* __restrict__ g1, const float* __restrict__ bb1,
    const float* __restrict__ m1, const float* __restrict__ v1,
    const float* __restrict__ W2, const float* __restrict__ lb2,
    const float* __restrict__ g2, const float* __restrict__ bb2,
    const float* __restrict__ m2, const float* __restrict__ v2)
{
    __shared__ float sW[64 * 64];
    __shared__ float sA[MT * SAP];

    int tid = threadIdx.x;
    int c0  = (tid & 15) * 4;
    int rt  = tid >> 4;
    int base = blockIdx.x * MT;

    float sc1v[4], sh1v[4], sc2v[4], sh2v[4];
    #pragma unroll
    for (int i = 0; i < 4; ++i) {
        int c = c0 + i;
        float s1 = g1[c] * rsqrtf(v1[c] + BN_EPS);
        sc1v[i] = s1;
        sh1v[i] = (lb1[c] - m1[c]) * s1 + bb1[c];
        float s2 = g2[c] * rsqrtf(v2[c] + BN_EPS);
        sc2v[i] = s2;
        sh2v[i] = (lb2[c] - m2[c]) * s2 + bb2[c];
    }

    for (int i = tid; i < 1024; i += 256)
        ((float4*)sW)[i] = ((const float4*)W1)[i];
    for (int i = tid; i < MT * 16; i += 256) {
        int r = i >> 4, cq = i & 15;
        int gr = base + r;
        float4 v = (gr < NN) ? ((const float4*)(agg + (size_t)gr * HH))[cq]
                             : make_float4(0.f, 0.f, 0.f, 0.f);
        *(float4*)&sA[r * SAP + cq * 4] = v;
    }
    __syncthreads();

    float acc1[8][4];
    #pragma unroll
    for (int i = 0; i < 8; ++i) { acc1[i][0]=0.f; acc1[i][1]=0.f; acc1[i][2]=0.f; acc1[i][3]=0.f; }
    for (int k4 = 0; k4 < 16; ++k4) {
        float4 a[8];
        #pragma unroll
        for (int i = 0; i < 8; ++i)
            a[i] = *(const float4*)&sA[(rt + 16 * i) * SAP + k4 * 4];
        #pragma unroll
        for (int kk = 0; kk < 4; ++kk) {
            float4 w = *(const float4*)&sW[(k4 * 4 + kk) * 64 + c0];
            #pragma unroll
            for (int i = 0; i < 8; ++i) {
                float av = (&a[i].x)[kk];
                acc1[i][0] = fmaf(av, w.x, acc1[i][0]);
                acc1[i][1] = fmaf(av, w.y, acc1[i][1]);
                acc1[i][2] = fmaf(av, w.z, acc1[i][2]);
                acc1[i][3] = fmaf(av, w.w, acc1[i][3]);
            }
        }
    }
    __syncthreads();

    #pragma unroll
    for (int i = 0; i < 8; ++i) {
        float4 z;
        z.x = fmaxf(fmaf(acc1[i][0], sc1v[0], sh1v[0]), 0.f);
        z.y = fmaxf(fmaf(acc1[i][1], sc1v[1], sh1v[1]), 0.f);
        z.z = fmaxf(fmaf(acc1[i][2], sc1v[2], sh1v[2]), 0.f);
        z.w = fmaxf(fmaf(acc1[i][3], sc1v[3], sh1v[3]), 0.f);
        *(float4*)&sA[(rt + 16 * i) * SAP + c0] = z;
    }
    for (int i = tid; i < 1024; i += 256)
        ((float4*)sW)[i] = ((const float4*)W2)[i];
    __syncthreads();

    float acc2[8][4];
    #pragma unroll
    for (int i = 0; i < 8; ++i) { acc2[i][0]=0.f; acc2[i][1]=0.f; acc2[i][2]=0.f; acc2[i][3]=0.f; }
    for (int k4 = 0; k4 < 16; ++k4) {
        float4 a[8];
        #pragma unroll
        for (int i = 0; i < 8; ++i)
            a[i] = *(const float4*)&sA[(rt + 16 * i) * SAP + k4 * 4];
        #pragma unroll
        for (int kk = 0; kk < 4; ++kk) {
            float4 w = *(const float4*)&sW[(k4 * 4 + kk) * 64 + c0];
            #pragma unroll
            for (int i = 0; i < 8; ++i) {
                float av = (&a[i].x)[kk];
                acc2[i][0] = fmaf(av, w.x, acc2[i][0]);
                acc2[i][1] = fmaf(av, w.y, acc2[i][1]);
                acc2[i][2] = fmaf(av, w.z, acc2[i][2]);
                acc2[i][3] = fmaf(av, w.w, acc2[i][3]);
            }
        }
    }

    #pragma unroll
    for (int i = 0; i < 8; ++i) {
        int gr = base + rt + 16 * i;
        if (gr < NN) {
            float zx = fmaxf(fmaf(acc2[i][0], sc2v[0], sh2v[0]), 0.f);
            float zy = fmaxf(fmaf(acc2[i][1], sc2v[1], sh2v[1]), 0.f);
            float zz = fmaxf(fmaf(acc2[i][2], sc2v[2], sh2v[2]), 0.f);
            float zw = fmaxf(fmaf(acc2[i][3], sc2v[3], sh2v[3]), 0.f);
            uint2 p;
            p.x = (unsigned int)f2bf(zx) | ((unsigned int)f2bf(zy) << 16);
            p.y = (unsigned int)f2bf(zz) | ((unsigned int)f2bf(zw) << 16);
            *(uint2*)&h_out[(size_t)gr * HH + c0] = p;
        }
    }
}

// ---------------------------------------------------------------------------
// Segment-sum pooling per layer (batch sorted, bf16 input, fp32 accumulate).
// ---------------------------------------------------------------------------
__global__ __launch_bounds__(256) void k_pool(const unsigned short* __restrict__ h,
                                              const int* __restrict__ batch,
                                              float* __restrict__ pooled, int layer)
{
    int g = blockIdx.x;
    int t = threadIdx.x;
    int c = t & 63;
    int q = t >> 6;
    int lo = 0, hi = NN;
    while (lo < hi) { int mid = (lo + hi) >> 1; if (batch[mid] < g) lo = mid + 1; else hi = mid; }
    int s = lo;
    hi = NN;
    while (lo < hi) { int mid = (lo + hi) >> 1; if (batch[mid] < g + 1) lo = mid + 1; else hi = mid; }
    int e = lo;
    float acc = 0.f;
    for (int n = s + q; n < e; n += 4) acc += bf2f(h[(size_t)n * HH + c]);
    __shared__ float red[256];
    red[t] = acc;
    __syncthreads();
    if (t < 64)
        pooled[(size_t)g * (LL * HH) + layer * HH + c] = red[c] + red[64 + c] + red[128 + c] + red[192 + c];
}

// ---------------------------------------------------------------------------
// Final MLP: relu(pooled @ lin1 + b1) @ lin2 + b2. One block per graph.
// ---------------------------------------------------------------------------
__global__ __launch_bounds__(64) void k_mlp(const float* __restrict__ pooled,
                                            const float* __restrict__ w1, const float* __restrict__ b1,
                                            const float* __restrict__ w2, const float* __restrict__ b2,
                                            float* __restrict__ out)
{
    int g = blockIdx.x, c = threadIdx.x;
    __shared__ float hh[64];
    float acc = b1[c];
    const float* p = pooled + g * (LL * HH);
    #pragma unroll 8
    for (int k = 0; k < LL * HH; ++k) acc = fmaf(p[k], w1[k * HH + c], acc);
    hh[c] = fmaxf(acc, 0.f);
    __syncthreads();
    if (c < CC) {
        float o = b2[c];
        #pragma unroll
        for (int k = 0; k < HH; ++k) o = fmaf(hh[k], w2[k * CC + c], o);
        out[g * CC + c] = o;
    }
}

// ---------------------------------------------------------------------------
extern "C" void kernel_launch(void* const* d_in, const int* in_sizes, int n_in,
                              void* d_out, int out_size, void* d_ws, size_t ws_size,
                              hipStream_t stream) {
    const float* x    = (const float*)d_in[0];
    const int*   ei   = (const int*)d_in[1];
    const int*   bat  = (const int*)d_in[2];
    const float* cW1  = (const float*)d_in[3];
    const float* cb1  = (const float*)d_in[4];
    const float* g1   = (const float*)d_in[5];
    const float* bb1  = (const float*)d_in[6];
    const float* m1   = (const float*)d_in[7];
    const float* v1   = (const float*)d_in[8];
    const float* cW2  = (const float*)d_in[9];
    const float* cb2  = (const float*)d_in[10];
    const float* g2   = (const float*)d_in[11];
    const float* bb2  = (const float*)d_in[12];
    const float* m2   = (const float*)d_in[13];
    const float* v2   = (const float*)d_in[14];
    const float* l1W  = (const float*)d_in[15];
    const float* l1b  = (const float*)d_in[16];
    const float* l2W  = (const float*)d_in[17];
    const float* l2b  = (const float*)d_in[18];

    const int* srcp = ei;            // edge_index[0]
    const int* dstp = ei + NE;       // edge_index[1]

    char* ws = (char*)d_ws;
    size_t off = 0;
    auto alloc = [&](size_t bytes) -> char* {
        char* p = ws + off;
        off += (bytes + 255) & ~size_t(255);
        return p;
    };
    unsigned short* xb   = (unsigned short*)alloc((size_t)NN * HH * 2);
    unsigned short* hb0  = (unsigned short*)alloc((size_t)NN * HH * 2);
    unsigned short* hb1  = (unsigned short*)alloc((size_t)NN * HH * 2);
    float* aggb    = (float*)alloc((size_t)NN * HH * sizeof(float));
    float* pooled  = (float*)alloc((size_t)GG * LL * HH * sizeof(float));
    int*   row_ptr = (int*)alloc((size_t)(NN + 1) * sizeof(int));
    int*   deg     = (int*)alloc((size_t)NN * sizeof(int));
    int*   incl    = (int*)alloc((size_t)NN * sizeof(int));
    int*   cursor  = (int*)alloc((size_t)NN * sizeof(int));
    int*   colx    = (int*)alloc((size_t)NE * sizeof(int));
    int*   bsum    = (int*)alloc(256 * sizeof(int));
    int*   boff    = (int*)alloc(256 * sizeof(int));

    hipMemsetAsync(deg, 0, (size_t)NN * sizeof(int), stream);
    hipMemsetAsync(cursor, 0, (size_t)NN * sizeof(int), stream);

    // CSR build + x cast (independent, same stream)
    k_hist<<<(NE + 255) / 256, 256, 0, stream>>>(dstp, deg);
    k_cast<<<NN * 16 / 256, 256, 0, stream>>>(x, xb);
    k_scan1<<<SCB, 256, 0, stream>>>(deg, incl, bsum);
    k_scan2<<<1, 256, 0, stream>>>(bsum, boff, row_ptr);
    k_scan3<<<SCB, 256, 0, stream>>>(deg, incl, boff, row_ptr);
    k_scatter<<<(NE + 255) / 256, 256, 0, stream>>>(srcp, dstp, row_ptr, cursor, colx);

    const unsigned short* hin = xb;
    unsigned short* bufs[2] = { hb0, hb1 };
    const int AGG_BLK = (NN + 31) / 32;        // 1563
    const int MLP_BLK = (NN + MT - 1) / MT;    // 391
    for (int l = 0; l < LL; ++l) {
        unsigned short* hout = bufs[l & 1];
        k_agg<<<AGG_BLK, 256, 0, stream>>>(hin, aggb, row_ptr, colx);
        k_mlp2<<<MLP_BLK, 256, 0, stream>>>(aggb, hout,
            cW1 + (size_t)l * HH * HH, cb1 + l * HH,
            g1 + l * HH, bb1 + l * HH, m1 + l * HH, v1 + l * HH,
            cW2 + (size_t)l * HH * HH, cb2 + l * HH,
            g2 + l * HH, bb2 + l * HH, m2 + l * HH, v2 + l * HH);
        k_pool<<<GG, 256, 0, stream>>>(hout, bat, pooled, l);
        hin = hout;
    }

    k_mlp<<<GG, 64, 0, stream>>>(pooled, l1W, l1b, l2W, l2b, (float*)d_out);
}

// Round 10
// 347.769 us; speedup vs baseline: 5.9666x; 1.1663x over previous
//
#include <hip/hip_runtime.h>

// Problem constants (from reference)
#define NN 50000
#define NE 800000
#define HH 64
#define LL 4
#define GG 500
#define CC 10
#define BN_EPS 1e-5f
#define SCB 200     // scan blocks (200*256 = 51200 >= 50000)
#define NPART 6250  // NN/8 dst nodes per XCD partition
#define ECHUNK 2048 // edges per chunk in partitioned hist/scatter
#define NCHUNK 391  // ceil(NE/ECHUNK)

// ---- bf16 helpers (storage-only precision cut; math stays fp32) ----
__device__ inline float bf2f(unsigned int u16) {
    union { unsigned int i; float f; } v; v.i = u16 << 16; return v.f;
}
__device__ inline unsigned short f2bf(float f) {
    union { float f; unsigned int i; } v; v.f = f;
    unsigned int u = v.i + 0x7fffu + ((v.i >> 16) & 1u);   // round-nearest-even
    return (unsigned short)(u >> 16);
}
__device__ inline void addrow8(float* acc, uint4 u) {
    #pragma unroll
    for (int q = 0; q < 4; ++q) {
        unsigned int w = (&u.x)[q];
        union { unsigned int i; float f; } lo, hi;
        lo.i = w << 16; hi.i = w & 0xffff0000u;
        acc[2 * q]     += lo.f;
        acc[2 * q + 1] += hi.f;
    }
}

// ---------------------------------------------------------------------------
// x (fp32) -> bf16 table for the gather path
// ---------------------------------------------------------------------------
__global__ __launch_bounds__(256) void k_cast(const float* __restrict__ x, unsigned short* __restrict__ xb) {
    int i = blockIdx.x * 256 + threadIdx.x;   // 3125*256 = 800000 float4 groups
    if (i < NN * 16) {
        float4 v = ((const float4*)x)[i];
        uint2 p;
        p.x = (unsigned int)f2bf(v.x) | ((unsigned int)f2bf(v.y) << 16);
        p.y = (unsigned int)f2bf(v.z) | ((unsigned int)f2bf(v.w) << 16);
        ((uint2*)xb)[i] = p;
    }
}

// ---------------------------------------------------------------------------
// CSR build, XCD-partitioned: blocks with (blockIdx&7)==p handle only dst in
// partition p -> deg/cursor/col lines are written from ONE XCD's L2 (no
// cross-XCD dirty-line ping-pong; R9 showed 17x write amplification).
// ---------------------------------------------------------------------------
__global__ __launch_bounds__(256) void k_hist8(const int* __restrict__ dst, int* __restrict__ deg) {
    int part  = blockIdx.x & 7;
    int chunk = blockIdx.x >> 3;
    int lo = part * NPART, hi = lo + NPART;
    int base = chunk * ECHUNK + threadIdx.x;
    #pragma unroll
    for (int i = 0; i < 8; ++i) {
        int e = base + i * 256;
        if (e < NE) {
            int d = dst[e];
            if (d >= lo && d < hi) atomicAdd(&deg[d], 1);
        }
    }
}

__global__ __launch_bounds__(256) void k_scan1(const int* __restrict__ deg, int* __restrict__ incl,
                                               int* __restrict__ bsum) {
    int t = threadIdx.x;
    int idx = blockIdx.x * 256 + t;
    __shared__ int s[256];
    int v = (idx < NN) ? deg[idx] : 0;
    s[t] = v;
    __syncthreads();
    for (int off = 1; off < 256; off <<= 1) {
        int u = (t >= off) ? s[t - off] : 0;
        __syncthreads();
        if (t >= off) s[t] += u;
        __syncthreads();
    }
    if (idx < NN) incl[idx] = s[t];
    if (t == 255) bsum[blockIdx.x] = s[255];
}

__global__ __launch_bounds__(256) void k_scan2(const int* __restrict__ bsum, int* __restrict__ boff,
                                               int* __restrict__ row_ptr) {
    int t = threadIdx.x;
    __shared__ int s[256];
    int v = (t < SCB) ? bsum[t] : 0;
    s[t] = v;
    __syncthreads();
    for (int off = 1; off < 256; off <<= 1) {
        int u = (t >= off) ? s[t - off] : 0;
        __syncthreads();
        if (t >= off) s[t] += u;
        __syncthreads();
    }
    if (t < SCB) boff[t] = s[t] - v;       // exclusive block offset
    if (t == 255) row_ptr[NN] = s[255];    // grand total
}

__global__ __launch_bounds__(256) void k_scan3(const int* __restrict__ deg, const int* __restrict__ incl,
                                               const int* __restrict__ boff, int* __restrict__ row_ptr) {
    int idx = blockIdx.x * 256 + threadIdx.x;
    if (idx < NN) row_ptr[idx] = incl[idx] - deg[idx] + boff[blockIdx.x];
}

__global__ __launch_bounds__(256) void k_scatter8(const int* __restrict__ src, const int* __restrict__ dst,
                                                  const int* __restrict__ row_ptr, int* __restrict__ cursor,
                                                  int* __restrict__ col) {
    int part  = blockIdx.x & 7;
    int chunk = blockIdx.x >> 3;
    int lo = part * NPART, hi = lo + NPART;
    int base = chunk * ECHUNK + threadIdx.x;
    #pragma unroll
    for (int i = 0; i < 8; ++i) {
        int e = base + i * 256;
        if (e < NE) {
            int d = dst[e];
            if (d >= lo && d < hi) {
                int pos = atomicAdd(&cursor[d], 1);
                col[row_ptr[d] + pos] = src[e];
            }
        }
    }
}

// ---------------------------------------------------------------------------
// Aggregation: agg[n] = h[n] + sum_{j->n} h[j]; bf16 in, fp32 accumulate,
// bf16 out. 8-lane group per node (row = 128B), 8 nodes/wave, x4 edge unroll.
// ---------------------------------------------------------------------------
__global__ __launch_bounds__(256) void k_agg(
    const unsigned short* __restrict__ hb, unsigned short* __restrict__ aggb,
    const int* __restrict__ row_ptr, const int* __restrict__ col)
{
    int tid  = threadIdx.x;
    int lane = tid & 63;
    int wave = tid >> 6;
    int gl   = lane & 7;    // lane within 8-group; owns features gl*8..gl*8+7
    int grp  = lane >> 3;   // node slot within wave (0..7)
    int n = blockIdx.x * 32 + wave * 8 + grp;
    if (n >= NN) return;

    const uint4* hv = (const uint4*)hb;    // 8 uint4 per 64-elem row
    float acc[8]  = {0.f, 0.f, 0.f, 0.f, 0.f, 0.f, 0.f, 0.f};
    float acc2[8] = {0.f, 0.f, 0.f, 0.f, 0.f, 0.f, 0.f, 0.f};
    addrow8(acc, hv[(size_t)n * 8 + gl]);

    int j = row_ptr[n], fin = row_ptr[n + 1];
    for (; j + 4 <= fin; j += 4) {
        int s0 = col[j], s1 = col[j + 1], s2 = col[j + 2], s3 = col[j + 3];
        uint4 u0 = hv[(size_t)s0 * 8 + gl];
        uint4 u1 = hv[(size_t)s1 * 8 + gl];
        uint4 u2 = hv[(size_t)s2 * 8 + gl];
        uint4 u3 = hv[(size_t)s3 * 8 + gl];
        addrow8(acc, u0);  addrow8(acc2, u1);
        addrow8(acc, u2);  addrow8(acc2, u3);
    }
    for (; j < fin; ++j)
        addrow8(acc, hv[(size_t)col[j] * 8 + gl]);

    #pragma unroll
    for (int q = 0; q < 8; ++q) acc[q] += acc2[q];

    uint4 o;
    o.x = (unsigned int)f2bf(acc[0]) | ((unsigned int)f2bf(acc[1]) << 16);
    o.y = (unsigned int)f2bf(acc[2]) | ((unsigned int)f2bf(acc[3]) << 16);
    o.z = (unsigned int)f2bf(acc[4]) | ((unsigned int)f2bf(acc[5]) << 16);
    o.w = (unsigned int)f2bf(acc[6]) | ((unsigned int)f2bf(acc[7]) << 16);
    ((uint4*)(aggb + (size_t)n * HH))[gl] = o;
}

// ---------------------------------------------------------------------------
// Dense MLP for one layer + FUSED pooling.
//   h_out(bf16) = relu(bn2(relu(bn1(agg@W1))@W2));
//   pooled[g][layer*64+c] += column-sums per graph segment in this tile
//   (batch sorted -> <=3-4 segments/128-row tile; 64 atomics per segment).
// ---------------------------------------------------------------------------
#define MT 128
#define SAP 68

__global__ __launch_bounds__(256) void k_mlp2(
    const unsigned short* __restrict__ agg, unsigned short* __restrict__ h_out,
    const int* __restrict__ batch, float* __restrict__ pooled, int layer,
    const float* __restrict__ W1, const float* __restrict__ lb1,
    const float* __restrict__ g1, const float* __restrict__ bb1,
    const float* __restrict__ m1, const float* __restrict__ v1,
    const float* __restrict__ W2, const float* __restrict__ lb2,
    const float* __restrict__ g2, const float* __restrict__ bb2,
    const float* __restrict__ m2, const float* __restrict__ v2)
{
    __shared__ float sW[64 * 64];     // weights; reused as pool-reduce scratch
    __shared__ float sA[MT * SAP];

    int tid = threadIdx.x;
    int c0  = (tid & 15) * 4;
    int rt  = tid >> 4;
    int base = blockIdx.x * MT;

    float sc1v[4], sh1v[4], sc2v[4], sh2v[4];
    #pragma unroll
    for (int i = 0; i < 4; ++i) {
        int c = c0 + i;
        float s1 = g1[c] * rsqrtf(v1[c] + BN_EPS);
        sc1v[i] = s1;
        sh1v[i] = (lb1[c] - m1[c]) * s1 + bb1[c];
        float s2 = g2[c] * rsqrtf(v2[c] + BN_EPS);
        sc2v[i] = s2;
        sh2v[i] = (lb2[c] - m2[c]) * s2 + bb2[c];
    }

    // stage W1 + agg tile (bf16 -> fp32)
    for (int i = tid; i < 1024; i += 256)
        ((float4*)sW)[i] = ((const float4*)W1)[i];
    for (int i = tid; i < MT * 8; i += 256) {
        int r = i >> 3, cq = i & 7;
        int gr = base + r;
        uint4 u = (gr < NN) ? ((const uint4*)(agg + (size_t)gr * HH))[cq]
                            : make_uint4(0, 0, 0, 0);
        float* dp = &sA[r * SAP + cq * 8];
        dp[0] = bf2f(u.x & 0xffffu); dp[1] = bf2f(u.x >> 16);
        dp[2] = bf2f(u.y & 0xffffu); dp[3] = bf2f(u.y >> 16);
        dp[4] = bf2f(u.z & 0xffffu); dp[5] = bf2f(u.z >> 16);
        dp[6] = bf2f(u.w & 0xffffu); dp[7] = bf2f(u.w >> 16);
    }
    __syncthreads();

    // ---- GEMM1
    float acc1[8][4];
    #pragma unroll
    for (int i = 0; i < 8; ++i) { acc1[i][0]=0.f; acc1[i][1]=0.f; acc1[i][2]=0.f; acc1[i][3]=0.f; }
    for (int k4 = 0; k4 < 16; ++k4) {
        float4 a[8];
        #pragma unroll
        for (int i = 0; i < 8; ++i)
            a[i] = *(const float4*)&sA[(rt + 16 * i) * SAP + k4 * 4];
        #pragma unroll
        for (int kk = 0; kk < 4; ++kk) {
            float4 w = *(const float4*)&sW[(k4 * 4 + kk) * 64 + c0];
            #pragma unroll
            for (int i = 0; i < 8; ++i) {
                float av = (&a[i].x)[kk];
                acc1[i][0] = fmaf(av, w.x, acc1[i][0]);
                acc1[i][1] = fmaf(av, w.y, acc1[i][1]);
                acc1[i][2] = fmaf(av, w.z, acc1[i][2]);
                acc1[i][3] = fmaf(av, w.w, acc1[i][3]);
            }
        }
    }
    __syncthreads();

    // z1 = relu(bn1(.)) -> sA ; stage W2
    #pragma unroll
    for (int i = 0; i < 8; ++i) {
        float4 z;
        z.x = fmaxf(fmaf(acc1[i][0], sc1v[0], sh1v[0]), 0.f);
        z.y = fmaxf(fmaf(acc1[i][1], sc1v[1], sh1v[1]), 0.f);
        z.z = fmaxf(fmaf(acc1[i][2], sc1v[2], sh1v[2]), 0.f);
        z.w = fmaxf(fmaf(acc1[i][3], sc1v[3], sh1v[3]), 0.f);
        *(float4*)&sA[(rt + 16 * i) * SAP + c0] = z;
    }
    for (int i = tid; i < 1024; i += 256)
        ((float4*)sW)[i] = ((const float4*)W2)[i];
    __syncthreads();

    // ---- GEMM2
    float acc2[8][4];
    #pragma unroll
    for (int i = 0; i < 8; ++i) { acc2[i][0]=0.f; acc2[i][1]=0.f; acc2[i][2]=0.f; acc2[i][3]=0.f; }
    for (int k4 = 0; k4 < 16; ++k4) {
        float4 a[8];
        #pragma unroll
        for (int i = 0; i < 8; ++i)
            a[i] = *(const float4*)&sA[(rt + 16 * i) * SAP + k4 * 4];
        #pragma unroll
        for (int kk = 0; kk < 4; ++kk) {
            float4 w = *(const float4*)&sW[(k4 * 4 + kk) * 64 + c0];
            #pragma unroll
            for (int i = 0; i < 8; ++i) {
                float av = (&a[i].x)[kk];
                acc2[i][0] = fmaf(av, w.x, acc2[i][0]);
                acc2[i][1] = fmaf(av, w.y, acc2[i][1]);
                acc2[i][2] = fmaf(av, w.z, acc2[i][2]);
                acc2[i][3] = fmaf(av, w.w, acc2[i][3]);
            }
        }
    }
    __syncthreads();   // all GEMM2 reads of sA/sW done before overwrite

    // epilogue: z2 = relu(bn2(.)) -> h_out (bf16) and sA (fp32, for pooling)
    #pragma unroll
    for (int i = 0; i < 8; ++i) {
        int gr = base + rt + 16 * i;
        float zx = fmaxf(fmaf(acc2[i][0], sc2v[0], sh2v[0]), 0.f);
        float zy = fmaxf(fmaf(acc2[i][1], sc2v[1], sh2v[1]), 0.f);
        float zz = fmaxf(fmaf(acc2[i][2], sc2v[2], sh2v[2]), 0.f);
        float zw = fmaxf(fmaf(acc2[i][3], sc2v[3], sh2v[3]), 0.f);
        *(float4*)&sA[(rt + 16 * i) * SAP + c0] = make_float4(zx, zy, zz, zw);
        if (gr < NN) {
            uint2 p;
            p.x = (unsigned int)f2bf(zx) | ((unsigned int)f2bf(zy) << 16);
            p.y = (unsigned int)f2bf(zz) | ((unsigned int)f2bf(zw) << 16);
            *(uint2*)&h_out[(size_t)gr * HH + c0] = p;
        }
    }
    __syncthreads();

    // ---- fused pooling: segment column-sums over this tile's graph segments
    int thi = base + MT; if (thi > NN) thi = NN;
    int gfirst = batch[base];
    int glast  = batch[thi - 1];
    int c = tid & 63;
    int q = tid >> 6;
    float* red = sW;   // reuse weight buffer as 256-float scratch
    for (int g = gfirst; g <= glast; ++g) {
        // local lower bounds within [base, thi)
        int lo = base, hi = thi;
        while (lo < hi) { int mid = (lo + hi) >> 1; if (batch[mid] < g) lo = mid + 1; else hi = mid; }
        int lo_g = lo;
        hi = thi;
        while (lo < hi) { int mid = (lo + hi) >> 1; if (batch[mid] < g + 1) lo = mid + 1; else hi = mid; }
        int hi_g = lo;
        float acc = 0.f;
        for (int r = lo_g + q; r < hi_g; r += 4) acc += sA[(r - base) * SAP + c];
        red[tid] = acc;
        __syncthreads();
        if (tid < 64)
            atomicAdd(&pooled[(size_t)g * (LL * HH) + layer * HH + c],
                      red[c] + red[64 + c] + red[128 + c] + red[192 + c]);
        __syncthreads();
    }
}

// ---------------------------------------------------------------------------
// Final MLP: relu(pooled @ lin1 + b1) @ lin2 + b2. One block per graph.
// ---------------------------------------------------------------------------
__global__ __launch_bounds__(64) void k_mlp(const float* __restrict__ pooled,
                                            const float* __restrict__ w1, const float* __restrict__ b1,
                                            const float* __restrict__ w2, const float* __restrict__ b2,
                                            float* __restrict__ out)
{
    int g = blockIdx.x, c = threadIdx.x;
    __shared__ float hh[64];
    float acc = b1[c];
    const float* p = pooled + g * (LL * HH);
    #pragma unroll 8
    for (int k = 0; k < LL * HH; ++k) acc = fmaf(p[k], w1[k * HH + c], acc);
    hh[c] = fmaxf(acc, 0.f);
    __syncthreads();
    if (c < CC) {
        float o = b2[c];
        #pragma unroll
        for (int k = 0; k < HH; ++k) o = fmaf(hh[k], w2[k * CC + c], o);
        out[g * CC + c] = o;
    }
}

// ---------------------------------------------------------------------------
extern "C" void kernel_launch(void* const* d_in, const int* in_sizes, int n_in,
                              void* d_out, int out_size, void* d_ws, size_t ws_size,
                              hipStream_t stream) {
    const float* x    = (const float*)d_in[0];
    const int*   ei   = (const int*)d_in[1];
    const int*   bat  = (const int*)d_in[2];
    const float* cW1  = (const float*)d_in[3];
    const float* cb1  = (const float*)d_in[4];
    const float* g1   = (const float*)d_in[5];
    const float* bb1  = (const float*)d_in[6];
    const float* m1   = (const float*)d_in[7];
    const float* v1   = (const float*)d_in[8];
    const float* cW2  = (const float*)d_in[9];
    const float* cb2  = (const float*)d_in[10];
    const float* g2   = (const float*)d_in[11];
    const float* bb2  = (const float*)d_in[12];
    const float* m2   = (const float*)d_in[13];
    const float* v2   = (const float*)d_in[14];
    const float* l1W  = (const float*)d_in[15];
    const float* l1b  = (const float*)d_in[16];
    const float* l2W  = (const float*)d_in[17];
    const float* l2b  = (const float*)d_in[18];

    const int* srcp = ei;            // edge_index[0]
    const int* dstp = ei + NE;       // edge_index[1]

    char* ws = (char*)d_ws;
    size_t off = 0;
    auto alloc = [&](size_t bytes) -> char* {
        char* p = ws + off;
        off += (bytes + 255) & ~size_t(255);
        return p;
    };
    unsigned short* xb   = (unsigned short*)alloc((size_t)NN * HH * 2);
    unsigned short* hb0  = (unsigned short*)alloc((size_t)NN * HH * 2);
    unsigned short* hb1  = (unsigned short*)alloc((size_t)NN * HH * 2);
    unsigned short* aggb = (unsigned short*)alloc((size_t)NN * HH * 2);
    float* pooled  = (float*)alloc((size_t)GG * LL * HH * sizeof(float));
    int*   row_ptr = (int*)alloc((size_t)(NN + 1) * sizeof(int));
    int*   deg     = (int*)alloc((size_t)NN * sizeof(int));
    int*   incl    = (int*)alloc((size_t)NN * sizeof(int));
    int*   cursor  = (int*)alloc((size_t)NN * sizeof(int));
    int*   colx    = (int*)alloc((size_t)NE * sizeof(int));
    int*   bsum    = (int*)alloc(256 * sizeof(int));
    int*   boff    = (int*)alloc(256 * sizeof(int));

    hipMemsetAsync(deg, 0, (size_t)NN * sizeof(int), stream);
    hipMemsetAsync(cursor, 0, (size_t)NN * sizeof(int), stream);
    hipMemsetAsync(pooled, 0, (size_t)GG * LL * HH * sizeof(float), stream);

    // CSR build (XCD-partitioned hist/scatter) + x cast
    k_hist8<<<8 * NCHUNK, 256, 0, stream>>>(dstp, deg);
    k_cast<<<NN * 16 / 256, 256, 0, stream>>>(x, xb);
    k_scan1<<<SCB, 256, 0, stream>>>(deg, incl, bsum);
    k_scan2<<<1, 256, 0, stream>>>(bsum, boff, row_ptr);
    k_scan3<<<SCB, 256, 0, stream>>>(deg, incl, boff, row_ptr);
    k_scatter8<<<8 * NCHUNK, 256, 0, stream>>>(srcp, dstp, row_ptr, cursor, colx);

    const unsigned short* hin = xb;
    unsigned short* bufs[2] = { hb0, hb1 };
    const int AGG_BLK = (NN + 31) / 32;        // 1563
    const int MLP_BLK = (NN + MT - 1) / MT;    // 391
    for (int l = 0; l < LL; ++l) {
        unsigned short* hout = bufs[l & 1];
        k_agg<<<AGG_BLK, 256, 0, stream>>>(hin, aggb, row_ptr, colx);
        k_mlp2<<<MLP_BLK, 256, 0, stream>>>(aggb, hout, bat, pooled, l,
            cW1 + (size_t)l * HH * HH, cb1 + l * HH,
            g1 + l * HH, bb1 + l * HH, m1 + l * HH, v1 + l * HH,
            cW2 + (size_t)l * HH * HH, cb2 + l * HH,
            g2 + l * HH, bb2 + l * HH, m2 + l * HH, v2 + l * HH);
        hin = hout;
    }

    k_mlp<<<GG, 64, 0, stream>>>(pooled, l1W, l1b, l2W, l2b, (float*)d_out);
}

// Round 12
// 315.085 us; speedup vs baseline: 6.5855x; 1.1037x over previous
//
#include <hip/hip_runtime.h>

// Problem constants (from reference)
#define NN 50000
#define NE 800000
#define HH 64
#define LL 4
#define GG 500
#define CC 10
#define BN_EPS 1e-5f
#define SCB 200     // scan blocks (200*256 = 51200 >= 50000)
#define NPART 6250  // NN/8 dst nodes per XCD partition
#define ECHUNK 2048 // edges per chunk in partitioned hist/scatter
#define NCHUNK 391  // ceil(NE/ECHUNK)

typedef short bf16x8 __attribute__((ext_vector_type(8)));
typedef float f32x4  __attribute__((ext_vector_type(4)));

// ---- bf16 helpers (storage-only precision cut; math stays fp32) ----
__device__ inline float bf2f(unsigned int u16) {
    union { unsigned int i; float f; } v; v.i = u16 << 16; return v.f;
}
__device__ inline unsigned short f2bf(float f) {
    union { float f; unsigned int i; } v; v.f = f;
    unsigned int u = v.i + 0x7fffu + ((v.i >> 16) & 1u);   // round-nearest-even
    return (unsigned short)(u >> 16);
}
__device__ inline void addrow8(float* acc, uint4 u) {
    #pragma unroll
    for (int q = 0; q < 4; ++q) {
        unsigned int w = (&u.x)[q];
        union { unsigned int i; float f; } lo, hi;
        lo.i = w << 16; hi.i = w & 0xffff0000u;
        acc[2 * q]     += lo.f;
        acc[2 * q + 1] += hi.f;
    }
}

// ---------------------------------------------------------------------------
// x (fp32) -> bf16 table for the gather path
// ---------------------------------------------------------------------------
__global__ __launch_bounds__(256) void k_cast(const float* __restrict__ x, unsigned short* __restrict__ xb) {
    int i = blockIdx.x * 256 + threadIdx.x;
    if (i < NN * 16) {
        float4 v = ((const float4*)x)[i];
        uint2 p;
        p.x = (unsigned int)f2bf(v.x) | ((unsigned int)f2bf(v.y) << 16);
        p.y = (unsigned int)f2bf(v.z) | ((unsigned int)f2bf(v.w) << 16);
        ((uint2*)xb)[i] = p;
    }
}

// ---------------------------------------------------------------------------
// Split-bf16 weight fragments, MFMA B-layout, fragment-ordered for coalesced
// wave loads: fragW[L][g][part][ct][kh] = 512 shorts (lane*8+j).
// B element (k, n): lane = (k>>3)*16 + n (within 16), j = k&7; k = kh*32 + ...
// ---------------------------------------------------------------------------
__global__ __launch_bounds__(256) void k_prepw(const float* __restrict__ cW1,
                                               const float* __restrict__ cW2,
                                               unsigned short* __restrict__ fragW)
{
    int idx = blockIdx.x * 256 + threadIdx.x;   // 32768 total
    if (idx >= LL * 2 * 4 * 2 * 64 * 8) return;
    int j    = idx & 7;
    int lane = (idx >> 3) & 63;
    int kh   = (idx >> 9) & 1;
    int ct   = (idx >> 10) & 3;
    int g    = (idx >> 12) & 1;
    int L    = idx >> 13;
    int k = kh * 32 + (lane >> 4) * 8 + j;
    int n = ct * 16 + (lane & 15);
    const float* W = (g == 0 ? cW1 : cW2) + (size_t)L * HH * HH;
    float w = W[k * HH + n];
    unsigned short hi = f2bf(w);
    unsigned short lo = f2bf(w - bf2f(hi));
    size_t fhi = ((size_t)L * 32 + ((g * 2 + 0) * 4 + ct) * 2 + kh) * 512 + lane * 8 + j;
    size_t flo = ((size_t)L * 32 + ((g * 2 + 1) * 4 + ct) * 2 + kh) * 512 + lane * 8 + j;
    fragW[fhi] = hi;
    fragW[flo] = lo;
}

// ---------------------------------------------------------------------------
// CSR build, XCD-partitioned (R10: kills cross-XCD dirty-line ping-pong).
// ---------------------------------------------------------------------------
__global__ __launch_bounds__(256) void k_hist8(const int* __restrict__ dst, int* __restrict__ deg) {
    int part  = blockIdx.x & 7;
    int chunk = blockIdx.x >> 3;
    int lo = part * NPART, hi = lo + NPART;
    int base = chunk * ECHUNK + threadIdx.x;
    #pragma unroll
    for (int i = 0; i < 8; ++i) {
        int e = base + i * 256;
        if (e < NE) {
            int d = dst[e];
            if (d >= lo && d < hi) atomicAdd(&deg[d], 1);
        }
    }
}

__global__ __launch_bounds__(256) void k_scan1(const int* __restrict__ deg, int* __restrict__ incl,
                                               int* __restrict__ bsum) {
    int t = threadIdx.x;
    int idx = blockIdx.x * 256 + t;
    __shared__ int s[256];
    int v = (idx < NN) ? deg[idx] : 0;
    s[t] = v;
    __syncthreads();
    for (int off = 1; off < 256; off <<= 1) {
        int u = (t >= off) ? s[t - off] : 0;
        __syncthreads();
        if (t >= off) s[t] += u;
        __syncthreads();
    }
    if (idx < NN) incl[idx] = s[t];
    if (t == 255) bsum[blockIdx.x] = s[255];
}

__global__ __launch_bounds__(256) void k_scan2(const int* __restrict__ bsum, int* __restrict__ boff,
                                               int* __restrict__ row_ptr) {
    int t = threadIdx.x;
    __shared__ int s[256];
    int v = (t < SCB) ? bsum[t] : 0;
    s[t] = v;
    __syncthreads();
    for (int off = 1; off < 256; off <<= 1) {
        int u = (t >= off) ? s[t - off] : 0;
        __syncthreads();
        if (t >= off) s[t] += u;
        __syncthreads();
    }
    if (t < SCB) boff[t] = s[t] - v;
    if (t == 255) row_ptr[NN] = s[255];
}

__global__ __launch_bounds__(256) void k_scan3(const int* __restrict__ deg, const int* __restrict__ incl,
                                               const int* __restrict__ boff, int* __restrict__ row_ptr) {
    int idx = blockIdx.x * 256 + threadIdx.x;
    if (idx < NN) row_ptr[idx] = incl[idx] - deg[idx] + boff[blockIdx.x];
}

__global__ __launch_bounds__(256) void k_scatter8(const int* __restrict__ src, const int* __restrict__ dst,
                                                  const int* __restrict__ row_ptr, int* __restrict__ cursor,
                                                  int* __restrict__ col) {
    int part  = blockIdx.x & 7;
    int chunk = blockIdx.x >> 3;
    int lo = part * NPART, hi = lo + NPART;
    int base = chunk * ECHUNK + threadIdx.x;
    #pragma unroll
    for (int i = 0; i < 8; ++i) {
        int e = base + i * 256;
        if (e < NE) {
            int d = dst[e];
            if (d >= lo && d < hi) {
                int pos = atomicAdd(&cursor[d], 1);
                col[row_ptr[d] + pos] = src[e];
            }
        }
    }
}

// ---------------------------------------------------------------------------
// Aggregation (unchanged from R10): bf16 in, fp32 accumulate, bf16 out.
// ---------------------------------------------------------------------------
__global__ __launch_bounds__(256) void k_agg(
    const unsigned short* __restrict__ hb, unsigned short* __restrict__ aggb,
    const int* __restrict__ row_ptr, const int* __restrict__ col)
{
    int tid  = threadIdx.x;
    int lane = tid & 63;
    int wave = tid >> 6;
    int gl   = lane & 7;
    int grp  = lane >> 3;
    int n = blockIdx.x * 32 + wave * 8 + grp;
    if (n >= NN) return;

    const uint4* hv = (const uint4*)hb;
    float acc[8]  = {0.f, 0.f, 0.f, 0.f, 0.f, 0.f, 0.f, 0.f};
    float acc2[8] = {0.f, 0.f, 0.f, 0.f, 0.f, 0.f, 0.f, 0.f};
    addrow8(acc, hv[(size_t)n * 8 + gl]);

    int j = row_ptr[n], fin = row_ptr[n + 1];
    for (; j + 4 <= fin; j += 4) {
        int s0 = col[j], s1 = col[j + 1], s2 = col[j + 2], s3 = col[j + 3];
        uint4 u0 = hv[(size_t)s0 * 8 + gl];
        uint4 u1 = hv[(size_t)s1 * 8 + gl];
        uint4 u2 = hv[(size_t)s2 * 8 + gl];
        uint4 u3 = hv[(size_t)s3 * 8 + gl];
        addrow8(acc, u0);  addrow8(acc2, u1);
        addrow8(acc, u2);  addrow8(acc2, u3);
    }
    for (; j < fin; ++j)
        addrow8(acc, hv[(size_t)col[j] * 8 + gl]);

    #pragma unroll
    for (int q = 0; q < 8; ++q) acc[q] += acc2[q];

    uint4 o;
    o.x = (unsigned int)f2bf(acc[0]) | ((unsigned int)f2bf(acc[1]) << 16);
    o.y = (unsigned int)f2bf(acc[2]) | ((unsigned int)f2bf(acc[3]) << 16);
    o.z = (unsigned int)f2bf(acc[4]) | ((unsigned int)f2bf(acc[5]) << 16);
    o.w = (unsigned int)f2bf(acc[6]) | ((unsigned int)f2bf(acc[7]) << 16);
    ((uint4*)(aggb + (size_t)n * HH))[gl] = o;
}

// ---------------------------------------------------------------------------
// MFMA MLP layer + fused pooling.
//   GEMM1: agg(bf16) @ (W1hi + W1lo)           -> z1 (fp32), split hi/lo
//   GEMM2: z1hi@W2hi + z1lo@W2hi + z1hi@W2lo   -> z2
// 128-node tile, 4 waves, wave = 32 rows x 64 cols = 8 MFMA 16x16 tiles.
// A-frag (16x16x32 bf16): lane kb*16+m holds row m, k = kb*8 + j.
// C/D: col = lane&15, row = (lane>>4)*4 + reg (m89-verified).
// ---------------------------------------------------------------------------
#define MT 128
#define SAB 80    // bf16 tile row stride in shorts (160B, 16B-aligned)
#define SOF 68    // fp32 out tile row stride in floats

__global__ __launch_bounds__(256) void k_mlp2(
    const unsigned short* __restrict__ agg, unsigned short* __restrict__ h_out,
    const int* __restrict__ batch, float* __restrict__ pooled, int layer,
    const unsigned short* __restrict__ fragW,
    const float* __restrict__ lb1, const float* __restrict__ g1,
    const float* __restrict__ bb1, const float* __restrict__ m1, const float* __restrict__ v1,
    const float* __restrict__ lb2, const float* __restrict__ g2,
    const float* __restrict__ bb2, const float* __restrict__ m2, const float* __restrict__ v2)
{
    __shared__ unsigned short sHi[128 * SAB];   // agg tile, then z1hi
    __shared__ unsigned short sLo[128 * SAB];   // z1lo
    __shared__ float sOut[128 * SOF];           // z2 fp32 (pooling + copy-out)
    __shared__ float red[256];

    int tid  = threadIdx.x;
    int lane = tid & 63;
    int wave = tid >> 6;
    int l15 = lane & 15, l4 = lane >> 4;
    int base = blockIdx.x * MT;
    int wrow = wave * 32;

    float sc1v[4], sh1v[4], sc2v[4], sh2v[4];
    #pragma unroll
    for (int ct = 0; ct < 4; ++ct) {
        int c = ct * 16 + l15;
        float s1 = g1[c] * rsqrtf(v1[c] + BN_EPS);
        sc1v[ct] = s1; sh1v[ct] = (lb1[c] - m1[c]) * s1 + bb1[c];
        float s2 = g2[c] * rsqrtf(v2[c] + BN_EPS);
        sc2v[ct] = s2; sh2v[ct] = (lb2[c] - m2[c]) * s2 + bb2[c];
    }

    // stage agg tile (bf16, padded rows)
    for (int i = tid; i < 128 * 8; i += 256) {
        int r = i >> 3, q = i & 7;
        int gr = base + r;
        uint4 u = (gr < NN) ? ((const uint4*)(agg + (size_t)gr * HH))[q] : make_uint4(0, 0, 0, 0);
        *(uint4*)&sHi[r * SAB + q * 8] = u;
    }
    __syncthreads();

    const bf16x8* fwv = (const bf16x8*)fragW + ((size_t)layer * 32) * 64;
    // B-frag for (g,part,ct,kh): fwv[(((g*2+part)*4+ct)*2+kh)*64 + lane]

    // ---- GEMM1
    bf16x8 a0[2][2];
    #pragma unroll
    for (int rt = 0; rt < 2; ++rt)
        #pragma unroll
        for (int kh = 0; kh < 2; ++kh)
            a0[rt][kh] = *(const bf16x8*)&sHi[(wrow + rt * 16 + l15) * SAB + kh * 32 + l4 * 8];

    f32x4 acc[2][4];
    #pragma unroll
    for (int rt = 0; rt < 2; ++rt)
        #pragma unroll
        for (int ct = 0; ct < 4; ++ct) {
            f32x4 c = {0.f, 0.f, 0.f, 0.f};
            #pragma unroll
            for (int kh = 0; kh < 2; ++kh) {
                c = __builtin_amdgcn_mfma_f32_16x16x32_bf16(a0[rt][kh], fwv[((0 * 4 + ct) * 2 + kh) * 64 + lane], c, 0, 0, 0); // W1hi
                c = __builtin_amdgcn_mfma_f32_16x16x32_bf16(a0[rt][kh], fwv[((1 * 4 + ct) * 2 + kh) * 64 + lane], c, 0, 0, 0); // W1lo
            }
            acc[rt][ct] = c;
        }
    __syncthreads();   // all waves done reading sHi

    // z1 = relu(bn1(acc)) split hi/lo -> sHi/sLo (A-layout, row-major shorts)
    #pragma unroll
    for (int rt = 0; rt < 2; ++rt)
        #pragma unroll
        for (int ct = 0; ct < 4; ++ct)
            #pragma unroll
            for (int rg = 0; rg < 4; ++rg) {
                int r = wrow + rt * 16 + l4 * 4 + rg;
                float z = fmaxf(fmaf(acc[rt][ct][rg], sc1v[ct], sh1v[ct]), 0.f);
                unsigned short hi = f2bf(z);
                sHi[r * SAB + ct * 16 + l15] = hi;
                sLo[r * SAB + ct * 16 + l15] = f2bf(z - bf2f(hi));
            }
    __syncthreads();

    // ---- GEMM2
    bf16x8 ah[2][2], al[2][2];
    #pragma unroll
    for (int rt = 0; rt < 2; ++rt)
        #pragma unroll
        for (int kh = 0; kh < 2; ++kh) {
            int off = (wrow + rt * 16 + l15) * SAB + kh * 32 + l4 * 8;
            ah[rt][kh] = *(const bf16x8*)&sHi[off];
            al[rt][kh] = *(const bf16x8*)&sLo[off];
        }
    #pragma unroll
    for (int rt = 0; rt < 2; ++rt)
        #pragma unroll
        for (int ct = 0; ct < 4; ++ct) {
            f32x4 c = {0.f, 0.f, 0.f, 0.f};
            #pragma unroll
            for (int kh = 0; kh < 2; ++kh) {
                bf16x8 bh = fwv[((2 * 4 + ct) * 2 + kh) * 64 + lane];   // W2hi (g=1,p=0)
                bf16x8 bl = fwv[((3 * 4 + ct) * 2 + kh) * 64 + lane];   // W2lo (g=1,p=1)
                c = __builtin_amdgcn_mfma_f32_16x16x32_bf16(ah[rt][kh], bh, c, 0, 0, 0);
                c = __builtin_amdgcn_mfma_f32_16x16x32_bf16(al[rt][kh], bh, c, 0, 0, 0);
                c = __builtin_amdgcn_mfma_f32_16x16x32_bf16(ah[rt][kh], bl, c, 0, 0, 0);
            }
            #pragma unroll
            for (int rg = 0; rg < 4; ++rg) {
                int r = wrow + rt * 16 + l4 * 4 + rg;
                float z = fmaxf(fmaf(c[rg], sc2v[ct], sh2v[ct]), 0.f);
                sOut[r * SOF + ct * 16 + l15] = z;
            }
        }
    __syncthreads();

    // h_out (bf16) copy-out, coalesced
    for (int i = tid; i < 128 * 8; i += 256) {
        int r = i >> 3, q = i & 7;
        int gr = base + r;
        if (gr < NN) {
            const float* sp = &sOut[r * SOF + q * 8];
            uint4 o;
            o.x = (unsigned int)f2bf(sp[0]) | ((unsigned int)f2bf(sp[1]) << 16);
            o.y = (unsigned int)f2bf(sp[2]) | ((unsigned int)f2bf(sp[3]) << 16);
            o.z = (unsigned int)f2bf(sp[4]) | ((unsigned int)f2bf(sp[5]) << 16);
            o.w = (unsigned int)f2bf(sp[6]) | ((unsigned int)f2bf(sp[7]) << 16);
            ((uint4*)(h_out + (size_t)gr * HH))[q] = o;
        }
    }

    // fused pooling over this tile's graph segments (batch sorted)
    int thi = base + MT; if (thi > NN) thi = NN;
    int gfirst = batch[base];
    int glast  = batch[thi - 1];
    int c = tid & 63;
    int q = tid >> 6;
    for (int g = gfirst; g <= glast; ++g) {
        int lo = base, hb = thi;
        while (lo < hb) { int mid = (lo + hb) >> 1; if (batch[mid] < g) lo = mid + 1; else hb = mid; }
        int lo_g = lo;
        hb = thi;
        while (lo < hb) { int mid = (lo + hb) >> 1; if (batch[mid] < g + 1) lo = mid + 1; else hb = mid; }
        int hi_g = lo;
        float a = 0.f;
        for (int r = lo_g + q; r < hi_g; r += 4) a += sOut[(r - base) * SOF + c];
        red[tid] = a;
        __syncthreads();
        if (tid < 64)
            atomicAdd(&pooled[(size_t)g * (LL * HH) + layer * HH + c],
                      red[c] + red[64 + c] + red[128 + c] + red[192 + c]);
        __syncthreads();
    }
}

// ---------------------------------------------------------------------------
// Final MLP: relu(pooled @ lin1 + b1) @ lin2 + b2. One block per graph.
// ---------------------------------------------------------------------------
__global__ __launch_bounds__(64) void k_mlp(const float* __restrict__ pooled,
                                            const float* __restrict__ w1, const float* __restrict__ b1,
                                            const float* __restrict__ w2, const float* __restrict__ b2,
                                            float* __restrict__ out)
{
    int g = blockIdx.x, c = threadIdx.x;
    __shared__ float hh[64];
    float acc = b1[c];
    const float* p = pooled + g * (LL * HH);
    #pragma unroll 8
    for (int k = 0; k < LL * HH; ++k) acc = fmaf(p[k], w1[k * HH + c], acc);
    hh[c] = fmaxf(acc, 0.f);
    __syncthreads();
    if (c < CC) {
        float o = b2[c];
        #pragma unroll
        for (int k = 0; k < HH; ++k) o = fmaf(hh[k], w2[k * CC + c], o);
        out[g * CC + c] = o;
    }
}

// ---------------------------------------------------------------------------
extern "C" void kernel_launch(void* const* d_in, const int* in_sizes, int n_in,
                              void* d_out, int out_size, void* d_ws, size_t ws_size,
                              hipStream_t stream) {
    const float* x    = (const float*)d_in[0];
    const int*   ei   = (const int*)d_in[1];
    const int*   bat  = (const int*)d_in[2];
    const float* cW1  = (const float*)d_in[3];
    const float* cb1  = (const float*)d_in[4];
    const float* g1   = (const float*)d_in[5];
    const float* bb1  = (const float*)d_in[6];
    const float* m1   = (const float*)d_in[7];
    const float* v1   = (const float*)d_in[8];
    const float* cW2  = (const float*)d_in[9];
    const float* cb2  = (const float*)d_in[10];
    const float* g2   = (const float*)d_in[11];
    const float* bb2  = (const float*)d_in[12];
    const float* m2   = (const float*)d_in[13];
    const float* v2   = (const float*)d_in[14];
    const float* l1W  = (const float*)d_in[15];
    const float* l1b  = (const float*)d_in[16];
    const float* l2W  = (const float*)d_in[17];
    const float* l2b  = (const float*)d_in[18];

    const int* srcp = ei;            // edge_index[0]
    const int* dstp = ei + NE;       // edge_index[1]

    char* ws = (char*)d_ws;
    size_t off = 0;
    auto alloc = [&](size_t bytes) -> char* {
        char* p = ws + off;
        off += (bytes + 255) & ~size_t(255);
        return p;
    };
    unsigned short* xb    = (unsigned short*)alloc((size_t)NN * HH * 2);
    unsigned short* hb0   = (unsigned short*)alloc((size_t)NN * HH * 2);
    unsigned short* hb1   = (unsigned short*)alloc((size_t)NN * HH * 2);
    unsigned short* aggb  = (unsigned short*)alloc((size_t)NN * HH * 2);
    unsigned short* fragW = (unsigned short*)alloc((size_t)LL * 32 * 512 * 2);
    float* pooled  = (float*)alloc((size_t)GG * LL * HH * sizeof(float));
    int*   row_ptr = (int*)alloc((size_t)(NN + 1) * sizeof(int));
    int*   deg     = (int*)alloc((size_t)NN * sizeof(int));
    int*   incl    = (int*)alloc((size_t)NN * sizeof(int));
    int*   cursor  = (int*)alloc((size_t)NN * sizeof(int));
    int*   colx    = (int*)alloc((size_t)NE * sizeof(int));
    int*   bsum    = (int*)alloc(256 * sizeof(int));
    int*   boff    = (int*)alloc(256 * sizeof(int));

    hipMemsetAsync(deg, 0, (size_t)NN * sizeof(int), stream);
    hipMemsetAsync(cursor, 0, (size_t)NN * sizeof(int), stream);
    hipMemsetAsync(pooled, 0, (size_t)GG * LL * HH * sizeof(float), stream);

    // CSR build (XCD-partitioned) + x cast + weight fragment prep
    k_hist8<<<8 * NCHUNK, 256, 0, stream>>>(dstp, deg);
    k_cast<<<NN * 16 / 256, 256, 0, stream>>>(x, xb);
    k_prepw<<<128, 256, 0, stream>>>(cW1, cW2, fragW);
    k_scan1<<<SCB, 256, 0, stream>>>(deg, incl, bsum);
    k_scan2<<<1, 256, 0, stream>>>(bsum, boff, row_ptr);
    k_scan3<<<SCB, 256, 0, stream>>>(deg, incl, boff, row_ptr);
    k_scatter8<<<8 * NCHUNK, 256, 0, stream>>>(srcp, dstp, row_ptr, cursor, colx);

    const unsigned short* hin = xb;
    unsigned short* bufs[2] = { hb0, hb1 };
    const int AGG_BLK = (NN + 31) / 32;        // 1563
    const int MLP_BLK = (NN + MT - 1) / MT;    // 391
    for (int l = 0; l < LL; ++l) {
        unsigned short* hout = bufs[l & 1];
        k_agg<<<AGG_BLK, 256, 0, stream>>>(hin, aggb, row_ptr, colx);
        k_mlp2<<<MLP_BLK, 256, 0, stream>>>(aggb, hout, bat, pooled, l, fragW,
            cb1 + l * HH, g1 + l * HH, bb1 + l * HH, m1 + l * HH, v1 + l * HH,
            cb2 + l * HH, g2 + l * HH, bb2 + l * HH, m2 + l * HH, v2 + l * HH);
        hin = hout;
    }

    k_mlp<<<GG, 64, 0, stream>>>(pooled, l1W, l1b, l2W, l2b, (float*)d_out);
}

// Round 13
// 314.505 us; speedup vs baseline: 6.5976x; 1.0018x over previous
//
#include <hip/hip_runtime.h>

// Problem constants (from reference)
#define NN 50000
#define NE 800000
#define HH 64
#define LL 4
#define GG 500
#define CC 10
#define BN_EPS 1e-5f
#define SCB 200     // scan blocks (200*256 = 51200 >= 50000)
#define NPART 6250  // NN/8 dst nodes per XCD partition
#define ECHUNK 2048 // edges per chunk in partitioned hist/scatter
#define NCHUNK 391  // ceil(NE/ECHUNK)
#define CASTB 3125  // k_prep: cast blocks

typedef short bf16x8 __attribute__((ext_vector_type(8)));
typedef float f32x4  __attribute__((ext_vector_type(4)));

// ---- bf16 helpers (storage-only precision cut; math stays fp32) ----
__device__ inline float bf2f(unsigned int u16) {
    union { unsigned int i; float f; } v; v.i = u16 << 16; return v.f;
}
__device__ inline unsigned short f2bf(float f) {
    union { float f; unsigned int i; } v; v.f = f;
    unsigned int u = v.i + 0x7fffu + ((v.i >> 16) & 1u);   // round-nearest-even
    return (unsigned short)(u >> 16);
}
__device__ inline void addrow8(float* acc, uint4 u) {
    #pragma unroll
    for (int q = 0; q < 4; ++q) {
        unsigned int w = (&u.x)[q];
        union { unsigned int i; float f; } lo, hi;
        lo.i = w << 16; hi.i = w & 0xffff0000u;
        acc[2 * q]     += lo.f;
        acc[2 * q + 1] += hi.f;
    }
}

// ---------------------------------------------------------------------------
// Fused prep: blocks [0,3125) cast x->bf16; blocks [3125,3253) pack split-bf16
// weight fragments (MFMA B-layout, fragment-ordered).
// ---------------------------------------------------------------------------
__global__ __launch_bounds__(256) void k_prep(const float* __restrict__ x, unsigned short* __restrict__ xb,
                                              const float* __restrict__ cW1, const float* __restrict__ cW2,
                                              unsigned short* __restrict__ fragW)
{
    if (blockIdx.x < CASTB) {
        int i = blockIdx.x * 256 + threadIdx.x;
        if (i < NN * 16) {
            float4 v = ((const float4*)x)[i];
            uint2 p;
            p.x = (unsigned int)f2bf(v.x) | ((unsigned int)f2bf(v.y) << 16);
            p.y = (unsigned int)f2bf(v.z) | ((unsigned int)f2bf(v.w) << 16);
            ((uint2*)xb)[i] = p;
        }
        return;
    }
    int idx = (blockIdx.x - CASTB) * 256 + threadIdx.x;   // 32768 total
    if (idx >= LL * 2 * 4 * 2 * 64 * 8) return;
    int j    = idx & 7;
    int lane = (idx >> 3) & 63;
    int kh   = (idx >> 9) & 1;
    int ct   = (idx >> 10) & 3;
    int g    = (idx >> 12) & 1;
    int L    = idx >> 13;
    int k = kh * 32 + (lane >> 4) * 8 + j;
    int n = ct * 16 + (lane & 15);
    const float* W = (g == 0 ? cW1 : cW2) + (size_t)L * HH * HH;
    float w = W[k * HH + n];
    unsigned short hi = f2bf(w);
    unsigned short lo = f2bf(w - bf2f(hi));
    size_t fhi = ((size_t)L * 32 + ((g * 2 + 0) * 4 + ct) * 2 + kh) * 512 + lane * 8 + j;
    size_t flo = ((size_t)L * 32 + ((g * 2 + 1) * 4 + ct) * 2 + kh) * 512 + lane * 8 + j;
    fragW[fhi] = hi;
    fragW[flo] = lo;
}

// ---------------------------------------------------------------------------
// CSR build, XCD-partitioned (R10: kills cross-XCD dirty-line ping-pong).
// ---------------------------------------------------------------------------
__global__ __launch_bounds__(256) void k_hist8(const int* __restrict__ dst, int* __restrict__ deg) {
    int part  = blockIdx.x & 7;
    int chunk = blockIdx.x >> 3;
    int lo = part * NPART, hi = lo + NPART;
    int base = chunk * ECHUNK + threadIdx.x;
    #pragma unroll
    for (int i = 0; i < 8; ++i) {
        int e = base + i * 256;
        if (e < NE) {
            int d = dst[e];
            if (d >= lo && d < hi) atomicAdd(&deg[d], 1);
        }
    }
}

__global__ __launch_bounds__(256) void k_scan1(const int* __restrict__ deg, int* __restrict__ incl,
                                               int* __restrict__ bsum) {
    int t = threadIdx.x;
    int idx = blockIdx.x * 256 + t;
    __shared__ int s[256];
    int v = (idx < NN) ? deg[idx] : 0;
    s[t] = v;
    __syncthreads();
    for (int off = 1; off < 256; off <<= 1) {
        int u = (t >= off) ? s[t - off] : 0;
        __syncthreads();
        if (t >= off) s[t] += u;
        __syncthreads();
    }
    if (idx < NN) incl[idx] = s[t];
    if (t == 255) bsum[blockIdx.x] = s[255];
}

// scan of block sums fused into the fixup pass: every block redundantly scans
// the 200 partials in LDS (cheap), then applies its own offset.
__global__ __launch_bounds__(256) void k_scan3f(const int* __restrict__ deg, const int* __restrict__ incl,
                                                const int* __restrict__ bsum, int* __restrict__ row_ptr) {
    int t = threadIdx.x;
    __shared__ int s[256];
    int v = (t < SCB) ? bsum[t] : 0;
    s[t] = v;
    __syncthreads();
    for (int off = 1; off < 256; off <<= 1) {
        int u = (t >= off) ? s[t - off] : 0;
        __syncthreads();
        if (t >= off) s[t] += u;
        __syncthreads();
    }
    int boff_b = (blockIdx.x == 0) ? 0 : s[blockIdx.x - 1];
    if (blockIdx.x == 0 && t == 0) row_ptr[NN] = s[SCB - 1];
    int idx = blockIdx.x * 256 + t;
    if (idx < NN) row_ptr[idx] = incl[idx] - deg[idx] + boff_b;
}

__global__ __launch_bounds__(256) void k_scatter8(const int* __restrict__ src, const int* __restrict__ dst,
                                                  const int* __restrict__ row_ptr, int* __restrict__ cursor,
                                                  int* __restrict__ col) {
    int part  = blockIdx.x & 7;
    int chunk = blockIdx.x >> 3;
    int lo = part * NPART, hi = lo + NPART;
    int base = chunk * ECHUNK + threadIdx.x;
    #pragma unroll
    for (int i = 0; i < 8; ++i) {
        int e = base + i * 256;
        if (e < NE) {
            int d = dst[e];
            if (d >= lo && d < hi) {
                int pos = atomicAdd(&cursor[d], 1);
                col[row_ptr[d] + pos] = src[e];
            }
        }
    }
}

// ---------------------------------------------------------------------------
// Aggregation: bf16 in, fp32 accumulate, bf16 out. 8-lane group per node
// (row = 128B), 8 nodes/wave. Unroll x8: 8 independent row-loads in flight
// per group before any dependent add (R12 showed k_agg ~50% of runtime and
// mixed bytes+latency bound -> attack latency with deeper MLP).
// ---------------------------------------------------------------------------
__global__ __launch_bounds__(256) void k_agg(
    const unsigned short* __restrict__ hb, unsigned short* __restrict__ aggb,
    const int* __restrict__ row_ptr, const int* __restrict__ col)
{
    int tid  = threadIdx.x;
    int lane = tid & 63;
    int wave = tid >> 6;
    int gl   = lane & 7;
    int grp  = lane >> 3;
    int n = blockIdx.x * 32 + wave * 8 + grp;
    if (n >= NN) return;

    const uint4* hv = (const uint4*)hb;
    float acc[8]  = {0.f, 0.f, 0.f, 0.f, 0.f, 0.f, 0.f, 0.f};
    float acc2[8] = {0.f, 0.f, 0.f, 0.f, 0.f, 0.f, 0.f, 0.f};
    addrow8(acc, hv[(size_t)n * 8 + gl]);

    int j = row_ptr[n], fin = row_ptr[n + 1];
    for (; j + 8 <= fin; j += 8) {
        int s0 = col[j],     s1 = col[j + 1], s2 = col[j + 2], s3 = col[j + 3];
        int s4 = col[j + 4], s5 = col[j + 5], s6 = col[j + 6], s7 = col[j + 7];
        uint4 u0 = hv[(size_t)s0 * 8 + gl];
        uint4 u1 = hv[(size_t)s1 * 8 + gl];
        uint4 u2 = hv[(size_t)s2 * 8 + gl];
        uint4 u3 = hv[(size_t)s3 * 8 + gl];
        uint4 u4 = hv[(size_t)s4 * 8 + gl];
        uint4 u5 = hv[(size_t)s5 * 8 + gl];
        uint4 u6 = hv[(size_t)s6 * 8 + gl];
        uint4 u7 = hv[(size_t)s7 * 8 + gl];
        addrow8(acc, u0);  addrow8(acc2, u1);
        addrow8(acc, u2);  addrow8(acc2, u3);
        addrow8(acc, u4);  addrow8(acc2, u5);
        addrow8(acc, u6);  addrow8(acc2, u7);
    }
    for (; j + 4 <= fin; j += 4) {
        int s0 = col[j], s1 = col[j + 1], s2 = col[j + 2], s3 = col[j + 3];
        uint4 u0 = hv[(size_t)s0 * 8 + gl];
        uint4 u1 = hv[(size_t)s1 * 8 + gl];
        uint4 u2 = hv[(size_t)s2 * 8 + gl];
        uint4 u3 = hv[(size_t)s3 * 8 + gl];
        addrow8(acc, u0);  addrow8(acc2, u1);
        addrow8(acc, u2);  addrow8(acc2, u3);
    }
    for (; j < fin; ++j)
        addrow8(acc, hv[(size_t)col[j] * 8 + gl]);

    #pragma unroll
    for (int q = 0; q < 8; ++q) acc[q] += acc2[q];

    uint4 o;
    o.x = (unsigned int)f2bf(acc[0]) | ((unsigned int)f2bf(acc[1]) << 16);
    o.y = (unsigned int)f2bf(acc[2]) | ((unsigned int)f2bf(acc[3]) << 16);
    o.z = (unsigned int)f2bf(acc[4]) | ((unsigned int)f2bf(acc[5]) << 16);
    o.w = (unsigned int)f2bf(acc[6]) | ((unsigned int)f2bf(acc[7]) << 16);
    ((uint4*)(aggb + (size_t)n * HH))[gl] = o;
}

// ---------------------------------------------------------------------------
// MFMA MLP layer + fused pooling (verified R12, absmax 1.0).
// ---------------------------------------------------------------------------
#define MT 128
#define SAB 80    // bf16 tile row stride in shorts (160B, 16B-aligned)
#define SOF 68    // fp32 out tile row stride in floats

__global__ __launch_bounds__(256) void k_mlp2(
    const unsigned short* __restrict__ agg, unsigned short* __restrict__ h_out,
    const int* __restrict__ batch, float* __restrict__ pooled, int layer,
    const unsigned short* __restrict__ fragW,
    const float* __restrict__ lb1, const float* __restrict__ g1,
    const float* __restrict__ bb1, const float* __restrict__ m1, const float* __restrict__ v1,
    const float* __restrict__ lb2, const float* __restrict__ g2,
    const float* __restrict__ bb2, const float* __restrict__ m2, const float* __restrict__ v2)
{
    __shared__ unsigned short sHi[128 * SAB];   // agg tile, then z1hi
    __shared__ unsigned short sLo[128 * SAB];   // z1lo
    __shared__ float sOut[128 * SOF];           // z2 fp32 (pooling + copy-out)
    __shared__ float red[256];

    int tid  = threadIdx.x;
    int lane = tid & 63;
    int wave = tid >> 6;
    int l15 = lane & 15, l4 = lane >> 4;
    int base = blockIdx.x * MT;
    int wrow = wave * 32;

    float sc1v[4], sh1v[4], sc2v[4], sh2v[4];
    #pragma unroll
    for (int ct = 0; ct < 4; ++ct) {
        int c = ct * 16 + l15;
        float s1 = g1[c] * rsqrtf(v1[c] + BN_EPS);
        sc1v[ct] = s1; sh1v[ct] = (lb1[c] - m1[c]) * s1 + bb1[c];
        float s2 = g2[c] * rsqrtf(v2[c] + BN_EPS);
        sc2v[ct] = s2; sh2v[ct] = (lb2[c] - m2[c]) * s2 + bb2[c];
    }

    // stage agg tile (bf16, padded rows)
    for (int i = tid; i < 128 * 8; i += 256) {
        int r = i >> 3, q = i & 7;
        int gr = base + r;
        uint4 u = (gr < NN) ? ((const uint4*)(agg + (size_t)gr * HH))[q] : make_uint4(0, 0, 0, 0);
        *(uint4*)&sHi[r * SAB + q * 8] = u;
    }
    __syncthreads();

    const bf16x8* fwv = (const bf16x8*)fragW + ((size_t)layer * 32) * 64;

    // ---- GEMM1
    bf16x8 a0[2][2];
    #pragma unroll
    for (int rt = 0; rt < 2; ++rt)
        #pragma unroll
        for (int kh = 0; kh < 2; ++kh)
            a0[rt][kh] = *(const bf16x8*)&sHi[(wrow + rt * 16 + l15) * SAB + kh * 32 + l4 * 8];

    f32x4 acc[2][4];
    #pragma unroll
    for (int rt = 0; rt < 2; ++rt)
        #pragma unroll
        for (int ct = 0; ct < 4; ++ct) {
            f32x4 c = {0.f, 0.f, 0.f, 0.f};
            #pragma unroll
            for (int kh = 0; kh < 2; ++kh) {
                c = __builtin_amdgcn_mfma_f32_16x16x32_bf16(a0[rt][kh], fwv[((0 * 4 + ct) * 2 + kh) * 64 + lane], c, 0, 0, 0); // W1hi
                c = __builtin_amdgcn_mfma_f32_16x16x32_bf16(a0[rt][kh], fwv[((1 * 4 + ct) * 2 + kh) * 64 + lane], c, 0, 0, 0); // W1lo
            }
            acc[rt][ct] = c;
        }
    __syncthreads();   // all waves done reading sHi

    // z1 = relu(bn1(acc)) split hi/lo -> sHi/sLo (A-layout, row-major shorts)
    #pragma unroll
    for (int rt = 0; rt < 2; ++rt)
        #pragma unroll
        for (int ct = 0; ct < 4; ++ct)
            #pragma unroll
            for (int rg = 0; rg < 4; ++rg) {
                int r = wrow + rt * 16 + l4 * 4 + rg;
                float z = fmaxf(fmaf(acc[rt][ct][rg], sc1v[ct], sh1v[ct]), 0.f);
                unsigned short hi = f2bf(z);
                sHi[r * SAB + ct * 16 + l15] = hi;
                sLo[r * SAB + ct * 16 + l15] = f2bf(z - bf2f(hi));
            }
    __syncthreads();

    // ---- GEMM2
    bf16x8 ah[2][2], al[2][2];
    #pragma unroll
    for (int rt = 0; rt < 2; ++rt)
        #pragma unroll
        for (int kh = 0; kh < 2; ++kh) {
            int off = (wrow + rt * 16 + l15) * SAB + kh * 32 + l4 * 8;
            ah[rt][kh] = *(const bf16x8*)&sHi[off];
            al[rt][kh] = *(const bf16x8*)&sLo[off];
        }
    #pragma unroll
    for (int rt = 0; rt < 2; ++rt)
        #pragma unroll
        for (int ct = 0; ct < 4; ++ct) {
            f32x4 c = {0.f, 0.f, 0.f, 0.f};
            #pragma unroll
            for (int kh = 0; kh < 2; ++kh) {
                bf16x8 bh = fwv[((2 * 4 + ct) * 2 + kh) * 64 + lane];   // W2hi
                bf16x8 bl = fwv[((3 * 4 + ct) * 2 + kh) * 64 + lane];   // W2lo
                c = __builtin_amdgcn_mfma_f32_16x16x32_bf16(ah[rt][kh], bh, c, 0, 0, 0);
                c = __builtin_amdgcn_mfma_f32_16x16x32_bf16(al[rt][kh], bh, c, 0, 0, 0);
                c = __builtin_amdgcn_mfma_f32_16x16x32_bf16(ah[rt][kh], bl, c, 0, 0, 0);
            }
            #pragma unroll
            for (int rg = 0; rg < 4; ++rg) {
                int r = wrow + rt * 16 + l4 * 4 + rg;
                float z = fmaxf(fmaf(c[rg], sc2v[ct], sh2v[ct]), 0.f);
                sOut[r * SOF + ct * 16 + l15] = z;
            }
        }
    __syncthreads();

    // h_out (bf16) copy-out, coalesced
    for (int i = tid; i < 128 * 8; i += 256) {
        int r = i >> 3, q = i & 7;
        int gr = base + r;
        if (gr < NN) {
            const float* sp = &sOut[r * SOF + q * 8];
            uint4 o;
            o.x = (unsigned int)f2bf(sp[0]) | ((unsigned int)f2bf(sp[1]) << 16);
            o.y = (unsigned int)f2bf(sp[2]) | ((unsigned int)f2bf(sp[3]) << 16);
            o.z = (unsigned int)f2bf(sp[4]) | ((unsigned int)f2bf(sp[5]) << 16);
            o.w = (unsigned int)f2bf(sp[6]) | ((unsigned int)f2bf(sp[7]) << 16);
            ((uint4*)(h_out + (size_t)gr * HH))[q] = o;
        }
    }

    // fused pooling over this tile's graph segments (batch sorted)
    int thi = base + MT; if (thi > NN) thi = NN;
    int gfirst = batch[base];
    int glast  = batch[thi - 1];
    int c = tid & 63;
    int q = tid >> 6;
    for (int g = gfirst; g <= glast; ++g) {
        int lo = base, hb = thi;
        while (lo < hb) { int mid = (lo + hb) >> 1; if (batch[mid] < g) lo = mid + 1; else hb = mid; }
        int lo_g = lo;
        hb = thi;
        while (lo < hb) { int mid = (lo + hb) >> 1; if (batch[mid] < g + 1) lo = mid + 1; else hb = mid; }
        int hi_g = lo;
        float a = 0.f;
        for (int r = lo_g + q; r < hi_g; r += 4) a += sOut[(r - base) * SOF + c];
        red[tid] = a;
        __syncthreads();
        if (tid < 64)
            atomicAdd(&pooled[(size_t)g * (LL * HH) + layer * HH + c],
                      red[c] + red[64 + c] + red[128 + c] + red[192 + c]);
        __syncthreads();
    }
}

// ---------------------------------------------------------------------------
// Final MLP: relu(pooled @ lin1 + b1) @ lin2 + b2. One block per graph.
// ---------------------------------------------------------------------------
__global__ __launch_bounds__(64) void k_mlp(const float* __restrict__ pooled,
                                            const float* __restrict__ w1, const float* __restrict__ b1,
                                            const float* __restrict__ w2, const float* __restrict__ b2,
                                            float* __restrict__ out)
{
    int g = blockIdx.x, c = threadIdx.x;
    __shared__ float hh[64];
    float acc = b1[c];
    const float* p = pooled + g * (LL * HH);
    #pragma unroll 8
    for (int k = 0; k < LL * HH; ++k) acc = fmaf(p[k], w1[k * HH + c], acc);
    hh[c] = fmaxf(acc, 0.f);
    __syncthreads();
    if (c < CC) {
        float o = b2[c];
        #pragma unroll
        for (int k = 0; k < HH; ++k) o = fmaf(hh[k], w2[k * CC + c], o);
        out[g * CC + c] = o;
    }
}

// ---------------------------------------------------------------------------
extern "C" void kernel_launch(void* const* d_in, const int* in_sizes, int n_in,
                              void* d_out, int out_size, void* d_ws, size_t ws_size,
                              hipStream_t stream) {
    const float* x    = (const float*)d_in[0];
    const int*   ei   = (const int*)d_in[1];
    const int*   bat  = (const int*)d_in[2];
    const float* cW1  = (const float*)d_in[3];
    const float* cb1  = (const float*)d_in[4];
    const float* g1   = (const float*)d_in[5];
    const float* bb1  = (const float*)d_in[6];
    const float* m1   = (const float*)d_in[7];
    const float* v1   = (const float*)d_in[8];
    const float* cW2  = (const float*)d_in[9];
    const float* cb2  = (const float*)d_in[10];
    const float* g2   = (const float*)d_in[11];
    const float* bb2  = (const float*)d_in[12];
    const float* m2   = (const float*)d_in[13];
    const float* v2   = (const float*)d_in[14];
    const float* l1W  = (const float*)d_in[15];
    const float* l1b  = (const float*)d_in[16];
    const float* l2W  = (const float*)d_in[17];
    const float* l2b  = (const float*)d_in[18];

    const int* srcp = ei;            // edge_index[0]
    const int* dstp = ei + NE;       // edge_index[1]

    char* ws = (char*)d_ws;
    size_t off = 0;
    auto alloc = [&](size_t bytes) -> char* {
        char* p = ws + off;
        off += (bytes + 255) & ~size_t(255);
        return p;
    };
    unsigned short* xb    = (unsigned short*)alloc((size_t)NN * HH * 2);
    unsigned short* hb0   = (unsigned short*)alloc((size_t)NN * HH * 2);
    unsigned short* hb1   = (unsigned short*)alloc((size_t)NN * HH * 2);
    unsigned short* aggb  = (unsigned short*)alloc((size_t)NN * HH * 2);
    unsigned short* fragW = (unsigned short*)alloc((size_t)LL * 32 * 512 * 2);
    // deg, cursor, pooled contiguous -> single memset covers all three
    int*   deg     = (int*)alloc((size_t)NN * sizeof(int));
    int*   cursor  = (int*)alloc((size_t)NN * sizeof(int));
    float* pooled  = (float*)alloc((size_t)GG * LL * HH * sizeof(float));
    size_t zspan   = (size_t)((char*)(pooled + (size_t)GG * LL * HH) - (char*)deg);
    int*   row_ptr = (int*)alloc((size_t)(NN + 1) * sizeof(int));
    int*   incl    = (int*)alloc((size_t)NN * sizeof(int));
    int*   colx    = (int*)alloc((size_t)NE * sizeof(int));
    int*   bsum    = (int*)alloc(256 * sizeof(int));

    hipMemsetAsync(deg, 0, zspan, stream);

    // CSR build (XCD-partitioned) + x cast + weight fragment prep
    k_hist8<<<8 * NCHUNK, 256, 0, stream>>>(dstp, deg);
    k_prep<<<CASTB + 128, 256, 0, stream>>>(x, xb, cW1, cW2, fragW);
    k_scan1<<<SCB, 256, 0, stream>>>(deg, incl, bsum);
    k_scan3f<<<SCB, 256, 0, stream>>>(deg, incl, bsum, row_ptr);
    k_scatter8<<<8 * NCHUNK, 256, 0, stream>>>(srcp, dstp, row_ptr, cursor, colx);

    const unsigned short* hin = xb;
    unsigned short* bufs[2] = { hb0, hb1 };
    const int AGG_BLK = (NN + 31) / 32;        // 1563
    const int MLP_BLK = (NN + MT - 1) / MT;    // 391
    for (int l = 0; l < LL; ++l) {
        unsigned short* hout = bufs[l & 1];
        k_agg<<<AGG_BLK, 256, 0, stream>>>(hin, aggb, row_ptr, colx);
        k_mlp2<<<MLP_BLK, 256, 0, stream>>>(aggb, hout, bat, pooled, l, fragW,
            cb1 + l * HH, g1 + l * HH, bb1 + l * HH, m1 + l * HH, v1 + l * HH,
            cb2 + l * HH, g2 + l * HH, bb2 + l * HH, m2 + l * HH, v2 + l * HH);
        hin = hout;
    }

    k_mlp<<<GG, 64, 0, stream>>>(pooled, l1W, l1b, l2W, l2b, (float*)d_out);
}